// Round 1
// baseline (567.326 us; speedup 1.0000x reference)
//
#include <hip/hip_runtime.h>
#include <hip/hip_bf16.h>

// Problem constants
#define C_NUM_CAMS 6
#define C_NUM_LEVELS 4
#define C_NUM_PTS 13
#define C_NUM_GROUPS 8
#define C_BS 2
#define C_NA 900
#define C_E 256
#define C_NSLOT 312      // C*L*P
#define C_NCOL 2496      // NSLOT * G
#define C_NANCH 1800     // BS*NA

// Level geometry
// H: 64,32,16,8  W: 176,88,44,22  HW: 11264,2816,704,176
// transposed-ws element bases (bf16 elements): level l starts at base[l]
#define LB0 0
#define LB1 34603008     // 12*11264*256
#define LB2 43253760     // +12*2816*256
#define LB3 45416448     // +12*704*256
#define FM_WS_ELEMS 45957120
#define FM_WS_BYTES 91914240ull
#define WGT_WS_BYTES 17971200ull   // 1800*2496*4
#define GRID_WS_BYTES 1123200ull   // 1800*78*8

// ---------------------------------------------------------------------------
// K1: NCHW f32 -> NHWC bf16 transpose of all 4 feature maps into ws
// flat grid over [level][img][ctile][ptile]; 64ch x 64pix LDS tiles
// blocks: 8448 + 2112 + 528 + 144 = 11232
// ---------------------------------------------------------------------------
__global__ __launch_bounds__(256) void dfa_transpose(
    const float* __restrict__ fm0, const float* __restrict__ fm1,
    const float* __restrict__ fm2, const float* __restrict__ fm3,
    __hip_bfloat16* __restrict__ out) {
  int id = blockIdx.x;
  const float* fm;
  int HW, ptiles;
  long long base;
  int rem;
  if (id < 8448)       { rem = id;         fm = fm0; HW = 11264; ptiles = 176; base = LB0; }
  else if (id < 10560) { rem = id - 8448;  fm = fm1; HW = 2816;  ptiles = 44;  base = LB1; }
  else if (id < 11088) { rem = id - 10560; fm = fm2; HW = 704;   ptiles = 11;  base = LB2; }
  else                 { rem = id - 11088; fm = fm3; HW = 176;   ptiles = 3;   base = LB3; }
  int img = rem / (ptiles * 4);
  int r2  = rem % (ptiles * 4);
  int ct  = r2 / ptiles;
  int pt  = r2 % ptiles;
  int c0 = ct * 64, pix0 = pt * 64;

  __shared__ float tile[64][65];
  int t = threadIdx.x;
  int tx = t & 63, ty = t >> 6;

  const float* src = fm + (size_t)(img * 256 + c0) * HW + pix0;
  if (pix0 + tx < HW) {
#pragma unroll
    for (int r = 0; r < 16; ++r) {
      int cl = r * 4 + ty;
      tile[cl][tx] = src[(size_t)cl * HW + tx];
    }
  }
  __syncthreads();
  // write: lanes vary channel (contiguous bf16)
  int cx = t & 63, py = t >> 6;
  __hip_bfloat16* dst = out + base + ((long long)img * HW + pix0) * 256 + c0;
#pragma unroll
  for (int r = 0; r < 16; ++r) {
    int pl = r * 4 + py;
    if (pix0 + pl < HW) {
      dst[(long long)pl * 256 + cx] = __float2bfloat16(tile[cx][pl]);
    }
  }
}

// ---------------------------------------------------------------------------
// K2a: fusion-weight logits GEMM + softmax.  8 anchors per block, 225 blocks.
// logits kept in LDS (8 x 2497 f32, padded stride), softmax over 312 slots
// per (anchor, group), normalized weights written to ws.
// ---------------------------------------------------------------------------
__global__ __launch_bounds__(256) void dfa_logits(
    const float* __restrict__ IF, const float* __restrict__ AE,
    const float* __restrict__ Wwfc, const float* __restrict__ bwfc,
    float* __restrict__ wgt) {
  __shared__ float feat_t[256][8];   // [d][a]
  __shared__ float llog[8 * 2497];   // padded stride
  __shared__ float inv_s[64];
  int t = threadIdx.x;
  int a0 = blockIdx.x * 8;

#pragma unroll
  for (int a = 0; a < 8; ++a) {
    int bn = a0 + a;
    feat_t[t][a] = IF[bn * 256 + t] + AE[bn * 256 + t];
  }
  __syncthreads();

  // two passes of 5 columns each: cols = t + {0..4}*256 and t + {5..9}*256
#pragma unroll
  for (int pass = 0; pass < 2; ++pass) {
    int cbase = pass * 5 * 256;
    float acc[8][5];
#pragma unroll
    for (int k = 0; k < 5; ++k) {
      int col = cbase + k * 256 + t;
      float bias = (col < C_NCOL) ? bwfc[col] : 0.f;
#pragma unroll
      for (int a = 0; a < 8; ++a) acc[a][k] = bias;
    }
    for (int d = 0; d < 256; ++d) {
      float4 fA = *(const float4*)&feat_t[d][0];
      float4 fB = *(const float4*)&feat_t[d][4];
      float fv[8] = {fA.x, fA.y, fA.z, fA.w, fB.x, fB.y, fB.z, fB.w};
      const float* wrow = Wwfc + (size_t)d * C_NCOL + cbase + t;
#pragma unroll
      for (int k = 0; k < 5; ++k) {
        int col = cbase + k * 256 + t;
        if (col < C_NCOL) {
          float wv = wrow[k * 256];
#pragma unroll
          for (int a = 0; a < 8; ++a) acc[a][k] = fmaf(fv[a], wv, acc[a][k]);
        }
      }
    }
#pragma unroll
    for (int k = 0; k < 5; ++k) {
      int col = cbase + k * 256 + t;
      if (col < C_NCOL) {
#pragma unroll
        for (int a = 0; a < 8; ++a) llog[a * 2497 + col] = acc[a][k];
      }
    }
  }
  __syncthreads();

  if (t < 64) {
    int a = t >> 3, g = t & 7;
    float m = -1e30f;
    for (int s = 0; s < C_NSLOT; ++s) m = fmaxf(m, llog[a * 2497 + s * 8 + g]);
    float sum = 0.f;
    for (int s = 0; s < C_NSLOT; ++s) {
      float e = expf(llog[a * 2497 + s * 8 + g] - m);
      llog[a * 2497 + s * 8 + g] = e;
      sum += e;
    }
    inv_s[t] = 1.f / sum;
  }
  __syncthreads();

#pragma unroll
  for (int a = 0; a < 8; ++a) {
    int bn = a0 + a;
    for (int cc = 0; cc < 10; ++cc) {
      int col = cc * 256 + t;
      if (col < C_NCOL)
        wgt[(size_t)bn * C_NCOL + col] = llog[a * 2497 + col] * inv_s[a * 8 + (col & 7)];
    }
  }
}

// ---------------------------------------------------------------------------
// K2b: keypoints (offset GEMM) + projection -> normalized grid coords
// block per anchor, 128 threads
// ---------------------------------------------------------------------------
__global__ __launch_bounds__(128) void dfa_points(
    const float* __restrict__ IF, const float* __restrict__ anchor,
    const float* __restrict__ Wkps, const float* __restrict__ bkps,
    const float* __restrict__ projm, float2* __restrict__ grid) {
  int bn = blockIdx.x;
  int b = bn / C_NA;
  int t = threadIdx.x;
  __shared__ float kp[13][3];
  if (t < 39) {
    float acc = bkps[t];
    const float* f = IF + (size_t)bn * 256;
    for (int d = 0; d < 256; ++d) acc = fmaf(f[d], Wkps[d * 39 + t], acc);
    int p = t / 3, ax = t % 3;
    kp[p][ax] = anchor[(size_t)bn * 256 + ax] + acc;
  }
  __syncthreads();
  if (t < 78) {
    int c = t / 13, p = t % 13;
    const float* M = projm + (size_t)(b * 6 + c) * 16;
    float kx = kp[p][0], ky = kp[p][1], kz = kp[p][2];
    float x = M[0] * kx + M[1] * ky + M[2] * kz + M[3];
    float y = M[4] * kx + M[5] * ky + M[6] * kz + M[7];
    float z = M[8] * kx + M[9] * ky + M[10] * kz + M[11];
    float zc = fmaxf(z, 1e-5f);
    float inv = 1.0f / zc;
    grid[(size_t)bn * 78 + t] = make_float2(x * inv, y * inv);
  }
}

// ---------------------------------------------------------------------------
// K3: aggregation.  Block per anchor (1800), 256 threads = thread per channel.
// Slot geometry precomputed into LDS; uniform skip of all-OOB slots; fused
// W_out matvec + bias + residual epilogue.
// MODE 0: bf16 NHWC ws.  MODE 1: f32 NCHW direct (fallback, small ws).
// ---------------------------------------------------------------------------
struct __align__(16) SlotInfo { int o[4]; float w[4]; };

template <int MODE>
__global__ __launch_bounds__(256) void dfa_agg(
    const __hip_bfloat16* __restrict__ fmws,
    const float* __restrict__ fm0, const float* __restrict__ fm1,
    const float* __restrict__ fm2, const float* __restrict__ fm3,
    const float2* __restrict__ grid, const float* __restrict__ wgt,
    const float* __restrict__ IF, const float* __restrict__ Wout,
    const float* __restrict__ bout, float* __restrict__ out) {
  int bn = blockIdx.x;
  int b = bn / C_NA;
  int t = threadIdx.x;

  __shared__ SlotInfo slot[C_NSLOT];
  __shared__ int sflag[C_NSLOT];
  __shared__ float swgt[C_NCOL];
  __shared__ float fused[256];

  for (int i = t; i < C_NCOL; i += 256) swgt[i] = wgt[(size_t)bn * C_NCOL + i];

  for (int s = t; s < C_NSLOT; s += 256) {
    int c = s / 52, r = s % 52, l = r / 13, p = r % 13;
    float2 g2 = grid[(size_t)bn * 78 + c * 13 + p];
    int Wi = (l == 0) ? 176 : (l == 1) ? 88 : (l == 2) ? 44 : 22;
    int Hi = (l == 0) ? 64 : (l == 1) ? 32 : (l == 2) ? 16 : 8;
    float Wf = (float)Wi, Hf = (float)Hi;
    float ix = ((g2.x + 1.0f) * Wf - 1.0f) * 0.5f;
    float iy = ((g2.y + 1.0f) * Hf - 1.0f) * 0.5f;
    float ix0 = floorf(ix), iy0 = floorf(iy);
    float wx1 = ix - ix0, wy1 = iy - iy0;
    float wx0 = 1.f - wx1, wy0 = 1.f - wy1;
    bool vx0 = (ix0 >= 0.f) && (ix0 < Wf);
    bool vx1 = (ix0 + 1.f >= 0.f) && (ix0 + 1.f < Wf);
    bool vy0 = (iy0 >= 0.f) && (iy0 < Hf);
    bool vy1 = (iy0 + 1.f >= 0.f) && (iy0 + 1.f < Hf);
    int xi0 = (int)fminf(fmaxf(ix0, 0.f), Wf - 1.f);
    int xi1 = (int)fminf(fmaxf(ix0 + 1.f, 0.f), Wf - 1.f);
    int yi0 = (int)fminf(fmaxf(iy0, 0.f), Hf - 1.f);
    int yi1 = (int)fminf(fmaxf(iy0 + 1.f, 0.f), Hf - 1.f);
    float w00 = (vx0 && vy0) ? wy0 * wx0 : 0.f;
    float w01 = (vx1 && vy0) ? wy0 * wx1 : 0.f;
    float w10 = (vx0 && vy1) ? wy1 * wx0 : 0.f;
    float w11 = (vx1 && vy1) ? wy1 * wx1 : 0.f;
    int img = b * 6 + c;
    int HW = Wi * Hi;
    SlotInfo si;
    if (MODE == 0) {
      int lb = (l == 0) ? LB0 : (l == 1) ? LB1 : (l == 2) ? LB2 : LB3;
      int ib = lb + img * HW * 256;
      si.o[0] = ib + (yi0 * Wi + xi0) * 256;
      si.o[1] = ib + (yi0 * Wi + xi1) * 256;
      si.o[2] = ib + (yi1 * Wi + xi0) * 256;
      si.o[3] = ib + (yi1 * Wi + xi1) * 256;
    } else {
      int ib = img * 256 * HW;
      si.o[0] = ib + yi0 * Wi + xi0;
      si.o[1] = ib + yi0 * Wi + xi1;
      si.o[2] = ib + yi1 * Wi + xi0;
      si.o[3] = ib + yi1 * Wi + xi1;
    }
    si.w[0] = w00; si.w[1] = w01; si.w[2] = w10; si.w[3] = w11;
    slot[s] = si;
    sflag[s] = (w00 + w01 + w10 + w11 == 0.f) ? -1 : l;
  }
  __syncthreads();

  int g = t >> 5;
  float acc = 0.f;
  for (int s = 0; s < C_NSLOT; ++s) {
    int fl = sflag[s];
    if (fl < 0) continue;   // uniform across block
    SlotInfo si = slot[s];
    float wg = swgt[s * 8 + g];
    float v0, v1, v2, v3;
    if (MODE == 0) {
      v0 = __bfloat162float(fmws[si.o[0] + t]);
      v1 = __bfloat162float(fmws[si.o[1] + t]);
      v2 = __bfloat162float(fmws[si.o[2] + t]);
      v3 = __bfloat162float(fmws[si.o[3] + t]);
    } else {
      const float* fp = (fl == 0) ? fm0 : (fl == 1) ? fm1 : (fl == 2) ? fm2 : fm3;
      int HW = (fl == 0) ? 11264 : (fl == 1) ? 2816 : (fl == 2) ? 704 : 176;
      v0 = fp[si.o[0] + t * HW];
      v1 = fp[si.o[1] + t * HW];
      v2 = fp[si.o[2] + t * HW];
      v3 = fp[si.o[3] + t * HW];
    }
    float sv = si.w[0] * v0;
    sv = fmaf(si.w[1], v1, sv);
    sv = fmaf(si.w[2], v2, sv);
    sv = fmaf(si.w[3], v3, sv);
    acc = fmaf(sv, wg, acc);
  }
  fused[t] = acc;
  __syncthreads();

  float o = bout[t] + IF[(size_t)bn * 256 + t];
#pragma unroll 4
  for (int d = 0; d < 256; ++d)
    o = fmaf(fused[d], Wout[d * 256 + t], o);
  out[(size_t)bn * 256 + t] = o;
}

// ---------------------------------------------------------------------------
extern "C" void kernel_launch(void* const* d_in, const int* in_sizes, int n_in,
                              void* d_out, int out_size, void* d_ws, size_t ws_size,
                              hipStream_t stream) {
  const float* IF     = (const float*)d_in[0];
  const float* anchor = (const float*)d_in[1];
  const float* AE     = (const float*)d_in[2];
  const float* fm0    = (const float*)d_in[3];
  const float* fm1    = (const float*)d_in[4];
  const float* fm2    = (const float*)d_in[5];
  const float* fm3    = (const float*)d_in[6];
  const float* projm  = (const float*)d_in[7];
  const float* Wkps   = (const float*)d_in[8];
  const float* bkps   = (const float*)d_in[9];
  const float* Wwfc   = (const float*)d_in[10];
  const float* bwfc   = (const float*)d_in[11];
  const float* Wout   = (const float*)d_in[12];
  const float* bout   = (const float*)d_in[13];
  float* out = (float*)d_out;
  char* ws = (char*)d_ws;

  bool full = ws_size >= (FM_WS_BYTES + WGT_WS_BYTES + GRID_WS_BYTES);
  if (full) {
    __hip_bfloat16* fmws = (__hip_bfloat16*)ws;
    float* wgt  = (float*)(ws + FM_WS_BYTES);
    float2* grd = (float2*)(ws + FM_WS_BYTES + WGT_WS_BYTES);
    dfa_transpose<<<11232, 256, 0, stream>>>(fm0, fm1, fm2, fm3, fmws);
    dfa_logits<<<225, 256, 0, stream>>>(IF, AE, Wwfc, bwfc, wgt);
    dfa_points<<<1800, 128, 0, stream>>>(IF, anchor, Wkps, bkps, projm, grd);
    dfa_agg<0><<<1800, 256, 0, stream>>>(fmws, fm0, fm1, fm2, fm3, grd, wgt,
                                         IF, Wout, bout, out);
  } else {
    float* wgt  = (float*)ws;
    float2* grd = (float2*)(ws + WGT_WS_BYTES);
    dfa_logits<<<225, 256, 0, stream>>>(IF, AE, Wwfc, bwfc, wgt);
    dfa_points<<<1800, 128, 0, stream>>>(IF, anchor, Wkps, bkps, projm, grd);
    dfa_agg<1><<<1800, 256, 0, stream>>>(nullptr, fm0, fm1, fm2, fm3, grd, wgt,
                                         IF, Wout, bout, out);
  }
}

// Round 2
// 271.728 us; speedup vs baseline: 2.0878x; 2.0878x over previous
//
#include <hip/hip_runtime.h>
#include <hip/hip_bf16.h>

// Problem constants
#define C_NUM_CAMS 6
#define C_NUM_LEVELS 4
#define C_NUM_PTS 13
#define C_NUM_GROUPS 8
#define C_BS 2
#define C_NA 900
#define C_E 256
#define C_NSLOT 312      // C*L*P
#define C_NCOL 2496      // NSLOT * G
#define C_NANCH 1800     // BS*NA

// Level geometry
// H: 64,32,16,8  W: 176,88,44,22  HW: 11264,2816,704,176
#define LB0 0
#define LB1 34603008     // 12*11264*256
#define LB2 43253760     // +12*2816*256
#define LB3 45416448     // +12*704*256
#define FM_WS_ELEMS 45957120
#define FM_WS_BYTES 91914240ull
#define WGT_WS_BYTES 17971200ull   // 1800*2496*4
#define GRID_WS_BYTES 1123200ull   // 1800*78*8

// ---------------------------------------------------------------------------
// K1: NCHW f32 -> NHWC bf16 transpose of all 4 feature maps into ws
// ---------------------------------------------------------------------------
__global__ __launch_bounds__(256) void dfa_transpose(
    const float* __restrict__ fm0, const float* __restrict__ fm1,
    const float* __restrict__ fm2, const float* __restrict__ fm3,
    __hip_bfloat16* __restrict__ out) {
  int id = blockIdx.x;
  const float* fm;
  int HW, ptiles;
  long long base;
  int rem;
  if (id < 8448)       { rem = id;         fm = fm0; HW = 11264; ptiles = 176; base = LB0; }
  else if (id < 10560) { rem = id - 8448;  fm = fm1; HW = 2816;  ptiles = 44;  base = LB1; }
  else if (id < 11088) { rem = id - 10560; fm = fm2; HW = 704;   ptiles = 11;  base = LB2; }
  else                 { rem = id - 11088; fm = fm3; HW = 176;   ptiles = 3;   base = LB3; }
  int img = rem / (ptiles * 4);
  int r2  = rem % (ptiles * 4);
  int ct  = r2 / ptiles;
  int pt  = r2 % ptiles;
  int c0 = ct * 64, pix0 = pt * 64;

  __shared__ float tile[64][65];
  int t = threadIdx.x;
  int tx = t & 63, ty = t >> 6;

  const float* src = fm + (size_t)(img * 256 + c0) * HW + pix0;
  if (pix0 + tx < HW) {
#pragma unroll
    for (int r = 0; r < 16; ++r) {
      int cl = r * 4 + ty;
      tile[cl][tx] = src[(size_t)cl * HW + tx];
    }
  }
  __syncthreads();
  int cx = t & 63, py = t >> 6;
  __hip_bfloat16* dst = out + base + ((long long)img * HW + pix0) * 256 + c0;
#pragma unroll
  for (int r = 0; r < 16; ++r) {
    int pl = r * 4 + py;
    if (pix0 + pl < HW) {
      dst[(long long)pl * 256 + cx] = __float2bfloat16(tile[cx][pl]);
    }
  }
}

// ---------------------------------------------------------------------------
// K2a-1: fusion-weight logits GEMM.  15 anchors x 256 cols per block.
// grid (120, 10); feat tile in LDS (16KB), acc[15] in regs, unrolled d-loop
// for load ILP.  Writes raw logits to wgt ws buffer.
// ---------------------------------------------------------------------------
__global__ __launch_bounds__(256) void dfa_logits_gemm(
    const float* __restrict__ IF, const float* __restrict__ AE,
    const float* __restrict__ Wwfc, const float* __restrict__ bwfc,
    float* __restrict__ logits) {
  __shared__ float feat_t[256][16];   // [d][a], a<15 valid
  int t = threadIdx.x;
  int a0 = blockIdx.x * 15;
  int col = blockIdx.y * 256 + t;
  bool cv = col < C_NCOL;

#pragma unroll
  for (int a = 0; a < 15; ++a) {
    int bn = a0 + a;
    feat_t[t][a] = IF[(size_t)bn * 256 + t] + AE[(size_t)bn * 256 + t];
  }
  feat_t[t][15] = 0.f;
  __syncthreads();

  float acc[15];
  float bias = cv ? bwfc[col] : 0.f;
#pragma unroll
  for (int a = 0; a < 15; ++a) acc[a] = bias;

  const float* wp = Wwfc + col;
#pragma unroll 8
  for (int d = 0; d < 256; ++d) {
    float wv = cv ? wp[(size_t)d * C_NCOL] : 0.f;
    float4 f0 = *(const float4*)&feat_t[d][0];
    float4 f1 = *(const float4*)&feat_t[d][4];
    float4 f2 = *(const float4*)&feat_t[d][8];
    float4 f3 = *(const float4*)&feat_t[d][12];
    acc[0]  = fmaf(f0.x, wv, acc[0]);
    acc[1]  = fmaf(f0.y, wv, acc[1]);
    acc[2]  = fmaf(f0.z, wv, acc[2]);
    acc[3]  = fmaf(f0.w, wv, acc[3]);
    acc[4]  = fmaf(f1.x, wv, acc[4]);
    acc[5]  = fmaf(f1.y, wv, acc[5]);
    acc[6]  = fmaf(f1.z, wv, acc[6]);
    acc[7]  = fmaf(f1.w, wv, acc[7]);
    acc[8]  = fmaf(f2.x, wv, acc[8]);
    acc[9]  = fmaf(f2.y, wv, acc[9]);
    acc[10] = fmaf(f2.z, wv, acc[10]);
    acc[11] = fmaf(f2.w, wv, acc[11]);
    acc[12] = fmaf(f3.x, wv, acc[12]);
    acc[13] = fmaf(f3.y, wv, acc[13]);
    acc[14] = fmaf(f3.z, wv, acc[14]);
  }

  if (cv) {
#pragma unroll
    for (int a = 0; a < 15; ++a)
      logits[(size_t)(a0 + a) * C_NCOL + col] = acc[a];
  }
}

// ---------------------------------------------------------------------------
// K2a-2: softmax over 312 slots per (anchor, group), in-place on wgt.
// Block per anchor; group g handled by 32 lanes of one wave.
// ---------------------------------------------------------------------------
__global__ __launch_bounds__(256) void dfa_softmax(float* __restrict__ wgt) {
  int bn = blockIdx.x;
  float* w = wgt + (size_t)bn * C_NCOL;
  __shared__ float buf[C_NCOL];
  int t = threadIdx.x;
  for (int i = t; i < C_NCOL; i += 256) buf[i] = w[i];
  __syncthreads();
  int g = t >> 5, lane = t & 31;
  float m = -1e30f;
  for (int s = lane; s < C_NSLOT; s += 32) m = fmaxf(m, buf[s * 8 + g]);
#pragma unroll
  for (int off = 16; off; off >>= 1) m = fmaxf(m, __shfl_xor(m, off, 32));
  float sum = 0.f;
  for (int s = lane; s < C_NSLOT; s += 32) {
    float e = expf(buf[s * 8 + g] - m);
    buf[s * 8 + g] = e;
    sum += e;
  }
#pragma unroll
  for (int off = 16; off; off >>= 1) sum += __shfl_xor(sum, off, 32);
  float inv = 1.f / sum;
  for (int s = lane; s < C_NSLOT; s += 32) w[s * 8 + g] = buf[s * 8 + g] * inv;
}

// ---------------------------------------------------------------------------
// K2b: keypoints (offset GEMM) + projection -> normalized grid coords
// ---------------------------------------------------------------------------
__global__ __launch_bounds__(128) void dfa_points(
    const float* __restrict__ IF, const float* __restrict__ anchor,
    const float* __restrict__ Wkps, const float* __restrict__ bkps,
    const float* __restrict__ projm, float2* __restrict__ grid) {
  int bn = blockIdx.x;
  int b = bn / C_NA;
  int t = threadIdx.x;
  __shared__ float kp[13][3];
  if (t < 39) {
    float acc = bkps[t];
    const float* f = IF + (size_t)bn * 256;
    for (int d = 0; d < 256; ++d) acc = fmaf(f[d], Wkps[d * 39 + t], acc);
    int p = t / 3, ax = t % 3;
    kp[p][ax] = anchor[(size_t)bn * 256 + ax] + acc;
  }
  __syncthreads();
  if (t < 78) {
    int c = t / 13, p = t % 13;
    const float* M = projm + (size_t)(b * 6 + c) * 16;
    float kx = kp[p][0], ky = kp[p][1], kz = kp[p][2];
    float x = M[0] * kx + M[1] * ky + M[2] * kz + M[3];
    float y = M[4] * kx + M[5] * ky + M[6] * kz + M[7];
    float z = M[8] * kx + M[9] * ky + M[10] * kz + M[11];
    float zc = fmaxf(z, 1e-5f);
    float inv = 1.0f / zc;
    grid[(size_t)bn * 78 + t] = make_float2(x * inv, y * inv);
  }
}

// ---------------------------------------------------------------------------
// K3: aggregation.  Block per anchor (1800), 256 threads = thread per channel.
// ---------------------------------------------------------------------------
struct __align__(16) SlotInfo { int o[4]; float w[4]; };

template <int MODE>
__global__ __launch_bounds__(256) void dfa_agg(
    const __hip_bfloat16* __restrict__ fmws,
    const float* __restrict__ fm0, const float* __restrict__ fm1,
    const float* __restrict__ fm2, const float* __restrict__ fm3,
    const float2* __restrict__ grid, const float* __restrict__ wgt,
    const float* __restrict__ IF, const float* __restrict__ Wout,
    const float* __restrict__ bout, float* __restrict__ out) {
  int bn = blockIdx.x;
  int b = bn / C_NA;
  int t = threadIdx.x;

  __shared__ SlotInfo slot[C_NSLOT];
  __shared__ int sflag[C_NSLOT];
  __shared__ float swgt[C_NCOL];
  __shared__ float fused[256];

  for (int i = t; i < C_NCOL; i += 256) swgt[i] = wgt[(size_t)bn * C_NCOL + i];

  for (int s = t; s < C_NSLOT; s += 256) {
    int c = s / 52, r = s % 52, l = r / 13, p = r % 13;
    float2 g2 = grid[(size_t)bn * 78 + c * 13 + p];
    int Wi = (l == 0) ? 176 : (l == 1) ? 88 : (l == 2) ? 44 : 22;
    int Hi = (l == 0) ? 64 : (l == 1) ? 32 : (l == 2) ? 16 : 8;
    float Wf = (float)Wi, Hf = (float)Hi;
    float ix = ((g2.x + 1.0f) * Wf - 1.0f) * 0.5f;
    float iy = ((g2.y + 1.0f) * Hf - 1.0f) * 0.5f;
    float ix0 = floorf(ix), iy0 = floorf(iy);
    float wx1 = ix - ix0, wy1 = iy - iy0;
    float wx0 = 1.f - wx1, wy0 = 1.f - wy1;
    bool vx0 = (ix0 >= 0.f) && (ix0 < Wf);
    bool vx1 = (ix0 + 1.f >= 0.f) && (ix0 + 1.f < Wf);
    bool vy0 = (iy0 >= 0.f) && (iy0 < Hf);
    bool vy1 = (iy0 + 1.f >= 0.f) && (iy0 + 1.f < Hf);
    int xi0 = (int)fminf(fmaxf(ix0, 0.f), Wf - 1.f);
    int xi1 = (int)fminf(fmaxf(ix0 + 1.f, 0.f), Wf - 1.f);
    int yi0 = (int)fminf(fmaxf(iy0, 0.f), Hf - 1.f);
    int yi1 = (int)fminf(fmaxf(iy0 + 1.f, 0.f), Hf - 1.f);
    float w00 = (vx0 && vy0) ? wy0 * wx0 : 0.f;
    float w01 = (vx1 && vy0) ? wy0 * wx1 : 0.f;
    float w10 = (vx0 && vy1) ? wy1 * wx0 : 0.f;
    float w11 = (vx1 && vy1) ? wy1 * wx1 : 0.f;
    int img = b * 6 + c;
    int HW = Wi * Hi;
    SlotInfo si;
    if (MODE == 0) {
      int lb = (l == 0) ? LB0 : (l == 1) ? LB1 : (l == 2) ? LB2 : LB3;
      int ib = lb + img * HW * 256;
      si.o[0] = ib + (yi0 * Wi + xi0) * 256;
      si.o[1] = ib + (yi0 * Wi + xi1) * 256;
      si.o[2] = ib + (yi1 * Wi + xi0) * 256;
      si.o[3] = ib + (yi1 * Wi + xi1) * 256;
    } else {
      int ib = img * 256 * HW;
      si.o[0] = ib + yi0 * Wi + xi0;
      si.o[1] = ib + yi0 * Wi + xi1;
      si.o[2] = ib + yi1 * Wi + xi0;
      si.o[3] = ib + yi1 * Wi + xi1;
    }
    si.w[0] = w00; si.w[1] = w01; si.w[2] = w10; si.w[3] = w11;
    slot[s] = si;
    sflag[s] = (w00 + w01 + w10 + w11 == 0.f) ? -1 : l;
  }
  __syncthreads();

  int g = t >> 5;
  float acc = 0.f;
  for (int s = 0; s < C_NSLOT; ++s) {
    int fl = sflag[s];
    if (fl < 0) continue;   // uniform across block
    SlotInfo si = slot[s];
    float wg = swgt[s * 8 + g];
    float v0, v1, v2, v3;
    if (MODE == 0) {
      v0 = __bfloat162float(fmws[si.o[0] + t]);
      v1 = __bfloat162float(fmws[si.o[1] + t]);
      v2 = __bfloat162float(fmws[si.o[2] + t]);
      v3 = __bfloat162float(fmws[si.o[3] + t]);
    } else {
      const float* fp = (fl == 0) ? fm0 : (fl == 1) ? fm1 : (fl == 2) ? fm2 : fm3;
      int HW = (fl == 0) ? 11264 : (fl == 1) ? 2816 : (fl == 2) ? 704 : 176;
      v0 = fp[si.o[0] + t * HW];
      v1 = fp[si.o[1] + t * HW];
      v2 = fp[si.o[2] + t * HW];
      v3 = fp[si.o[3] + t * HW];
    }
    float sv = si.w[0] * v0;
    sv = fmaf(si.w[1], v1, sv);
    sv = fmaf(si.w[2], v2, sv);
    sv = fmaf(si.w[3], v3, sv);
    acc = fmaf(sv, wg, acc);
  }
  fused[t] = acc;
  __syncthreads();

  float o = bout[t] + IF[(size_t)bn * 256 + t];
#pragma unroll 4
  for (int d = 0; d < 256; ++d)
    o = fmaf(fused[d], Wout[d * 256 + t], o);
  out[(size_t)bn * 256 + t] = o;
}

// ---------------------------------------------------------------------------
extern "C" void kernel_launch(void* const* d_in, const int* in_sizes, int n_in,
                              void* d_out, int out_size, void* d_ws, size_t ws_size,
                              hipStream_t stream) {
  const float* IF     = (const float*)d_in[0];
  const float* anchor = (const float*)d_in[1];
  const float* AE     = (const float*)d_in[2];
  const float* fm0    = (const float*)d_in[3];
  const float* fm1    = (const float*)d_in[4];
  const float* fm2    = (const float*)d_in[5];
  const float* fm3    = (const float*)d_in[6];
  const float* projm  = (const float*)d_in[7];
  const float* Wkps   = (const float*)d_in[8];
  const float* bkps   = (const float*)d_in[9];
  const float* Wwfc   = (const float*)d_in[10];
  const float* bwfc   = (const float*)d_in[11];
  const float* Wout   = (const float*)d_in[12];
  const float* bout   = (const float*)d_in[13];
  float* out = (float*)d_out;
  char* ws = (char*)d_ws;

  bool full = ws_size >= (FM_WS_BYTES + WGT_WS_BYTES + GRID_WS_BYTES);
  if (full) {
    __hip_bfloat16* fmws = (__hip_bfloat16*)ws;
    float* wgt  = (float*)(ws + FM_WS_BYTES);
    float2* grd = (float2*)(ws + FM_WS_BYTES + WGT_WS_BYTES);
    dfa_transpose<<<11232, 256, 0, stream>>>(fm0, fm1, fm2, fm3, fmws);
    dfa_logits_gemm<<<dim3(120, 10), 256, 0, stream>>>(IF, AE, Wwfc, bwfc, wgt);
    dfa_softmax<<<1800, 256, 0, stream>>>(wgt);
    dfa_points<<<1800, 128, 0, stream>>>(IF, anchor, Wkps, bkps, projm, grd);
    dfa_agg<0><<<1800, 256, 0, stream>>>(fmws, fm0, fm1, fm2, fm3, grd, wgt,
                                         IF, Wout, bout, out);
  } else {
    float* wgt  = (float*)ws;
    float2* grd = (float2*)(ws + WGT_WS_BYTES);
    dfa_logits_gemm<<<dim3(120, 10), 256, 0, stream>>>(IF, AE, Wwfc, bwfc, wgt);
    dfa_softmax<<<1800, 256, 0, stream>>>(wgt);
    dfa_points<<<1800, 128, 0, stream>>>(IF, anchor, Wkps, bkps, projm, grd);
    dfa_agg<1><<<1800, 256, 0, stream>>>(nullptr, fm0, fm1, fm2, fm3, grd, wgt,
                                         IF, Wout, bout, out);
  }
}

// Round 3
// 268.573 us; speedup vs baseline: 2.1124x; 1.0117x over previous
//
#include <hip/hip_runtime.h>
#include <hip/hip_bf16.h>

// Problem constants
#define C_NUM_CAMS 6
#define C_NUM_LEVELS 4
#define C_NUM_PTS 13
#define C_NUM_GROUPS 8
#define C_BS 2
#define C_NA 900
#define C_E 256
#define C_NSLOT 312      // C*L*P
#define C_NCOL 2496      // NSLOT * G
#define C_NANCH 1800     // BS*NA

// Level geometry: H 64,32,16,8; W 176,88,44,22; HW 11264,2816,704,176
#define LB0 0
#define LB1 34603008     // 12*11264*256
#define LB2 43253760     // +12*2816*256
#define LB3 45416448     // +12*704*256
#define FM_WS_BYTES 91914240ull
#define WGT_WS_BYTES 17971200ull   // 1800*2496*4
#define GRID_WS_BYTES 1123200ull   // 1800*78*8

static __device__ __forceinline__ unsigned short f2bf(float f) {
  __hip_bfloat16 h = __float2bfloat16(f);
  return *reinterpret_cast<unsigned short*>(&h);
}
static __device__ __forceinline__ float bf2f(unsigned short u) {
  unsigned int v = ((unsigned int)u) << 16;
  float f;
  __builtin_memcpy(&f, &v, 4);
  return f;
}

// ---------------------------------------------------------------------------
// K1: NCHW f32 -> NHWC bf16 transpose of all 4 feature maps into ws
// ---------------------------------------------------------------------------
__global__ __launch_bounds__(256) void dfa_transpose(
    const float* __restrict__ fm0, const float* __restrict__ fm1,
    const float* __restrict__ fm2, const float* __restrict__ fm3,
    __hip_bfloat16* __restrict__ out) {
  int id = blockIdx.x;
  const float* fm;
  int HW, ptiles;
  long long base;
  int rem;
  if (id < 8448)       { rem = id;         fm = fm0; HW = 11264; ptiles = 176; base = LB0; }
  else if (id < 10560) { rem = id - 8448;  fm = fm1; HW = 2816;  ptiles = 44;  base = LB1; }
  else if (id < 11088) { rem = id - 10560; fm = fm2; HW = 704;   ptiles = 11;  base = LB2; }
  else                 { rem = id - 11088; fm = fm3; HW = 176;   ptiles = 3;   base = LB3; }
  int img = rem / (ptiles * 4);
  int r2  = rem % (ptiles * 4);
  int ct  = r2 / ptiles;
  int pt  = r2 % ptiles;
  int c0 = ct * 64, pix0 = pt * 64;

  __shared__ float tile[64][65];
  int t = threadIdx.x;
  int tx = t & 63, ty = t >> 6;

  const float* src = fm + (size_t)(img * 256 + c0) * HW + pix0;
  if (pix0 + tx < HW) {
#pragma unroll
    for (int r = 0; r < 16; ++r) {
      int cl = r * 4 + ty;
      tile[cl][tx] = src[(size_t)cl * HW + tx];
    }
  }
  __syncthreads();
  // write: ushort2 packed bf16 pairs (channel pairs contiguous)
  int cx2 = (t & 31) * 2;
  int py8 = t >> 5;
  __hip_bfloat16* dst = out + base + ((long long)img * HW + pix0) * 256 + c0;
#pragma unroll
  for (int r = 0; r < 8; ++r) {
    int pl = r * 8 + py8;
    if (pix0 + pl < HW) {
      ushort2 u;
      u.x = f2bf(tile[cx2][pl]);
      u.y = f2bf(tile[cx2 + 1][pl]);
      *reinterpret_cast<ushort2*>(&dst[(long long)pl * 256 + cx2]) = u;
    }
  }
}

// ---------------------------------------------------------------------------
// K2a-1: fusion-weight logits GEMM.  15 anchors x 256 cols per block.
// ---------------------------------------------------------------------------
__global__ __launch_bounds__(256) void dfa_logits_gemm(
    const float* __restrict__ IF, const float* __restrict__ AE,
    const float* __restrict__ Wwfc, const float* __restrict__ bwfc,
    float* __restrict__ logits) {
  __shared__ float feat_t[256][16];   // [d][a], a<15 valid
  int t = threadIdx.x;
  int a0 = blockIdx.x * 15;
  int col = blockIdx.y * 256 + t;
  bool cv = col < C_NCOL;

#pragma unroll
  for (int a = 0; a < 15; ++a) {
    int bn = a0 + a;
    feat_t[t][a] = IF[(size_t)bn * 256 + t] + AE[(size_t)bn * 256 + t];
  }
  feat_t[t][15] = 0.f;
  __syncthreads();

  float acc[15];
  float bias = cv ? bwfc[col] : 0.f;
#pragma unroll
  for (int a = 0; a < 15; ++a) acc[a] = bias;

  const float* wp = Wwfc + col;
#pragma unroll 8
  for (int d = 0; d < 256; ++d) {
    float wv = cv ? wp[(size_t)d * C_NCOL] : 0.f;
    float4 f0 = *(const float4*)&feat_t[d][0];
    float4 f1 = *(const float4*)&feat_t[d][4];
    float4 f2 = *(const float4*)&feat_t[d][8];
    float4 f3 = *(const float4*)&feat_t[d][12];
    acc[0]  = fmaf(f0.x, wv, acc[0]);
    acc[1]  = fmaf(f0.y, wv, acc[1]);
    acc[2]  = fmaf(f0.z, wv, acc[2]);
    acc[3]  = fmaf(f0.w, wv, acc[3]);
    acc[4]  = fmaf(f1.x, wv, acc[4]);
    acc[5]  = fmaf(f1.y, wv, acc[5]);
    acc[6]  = fmaf(f1.z, wv, acc[6]);
    acc[7]  = fmaf(f1.w, wv, acc[7]);
    acc[8]  = fmaf(f2.x, wv, acc[8]);
    acc[9]  = fmaf(f2.y, wv, acc[9]);
    acc[10] = fmaf(f2.z, wv, acc[10]);
    acc[11] = fmaf(f2.w, wv, acc[11]);
    acc[12] = fmaf(f3.x, wv, acc[12]);
    acc[13] = fmaf(f3.y, wv, acc[13]);
    acc[14] = fmaf(f3.z, wv, acc[14]);
  }

  if (cv) {
#pragma unroll
    for (int a = 0; a < 15; ++a)
      logits[(size_t)(a0 + a) * C_NCOL + col] = acc[a];
  }
}

// ---------------------------------------------------------------------------
// K2a-2: softmax over 312 slots per (anchor, group), in-place on wgt.
// ---------------------------------------------------------------------------
__global__ __launch_bounds__(256) void dfa_softmax(float* __restrict__ wgt) {
  int bn = blockIdx.x;
  float* w = wgt + (size_t)bn * C_NCOL;
  __shared__ float buf[C_NCOL];
  int t = threadIdx.x;
  for (int i = t; i < C_NCOL; i += 256) buf[i] = w[i];
  __syncthreads();
  int g = t >> 5, lane = t & 31;
  float m = -1e30f;
  for (int s = lane; s < C_NSLOT; s += 32) m = fmaxf(m, buf[s * 8 + g]);
#pragma unroll
  for (int off = 16; off; off >>= 1) m = fmaxf(m, __shfl_xor(m, off, 32));
  float sum = 0.f;
  for (int s = lane; s < C_NSLOT; s += 32) {
    float e = expf(buf[s * 8 + g] - m);
    buf[s * 8 + g] = e;
    sum += e;
  }
#pragma unroll
  for (int off = 16; off; off >>= 1) sum += __shfl_xor(sum, off, 32);
  float inv = 1.f / sum;
  for (int s = lane; s < C_NSLOT; s += 32) w[s * 8 + g] = buf[s * 8 + g] * inv;
}

// ---------------------------------------------------------------------------
// K2b: keypoints (offset GEMM) + projection -> normalized grid coords
// ---------------------------------------------------------------------------
__global__ __launch_bounds__(128) void dfa_points(
    const float* __restrict__ IF, const float* __restrict__ anchor,
    const float* __restrict__ Wkps, const float* __restrict__ bkps,
    const float* __restrict__ projm, float2* __restrict__ grid) {
  int bn = blockIdx.x;
  int b = bn / C_NA;
  int t = threadIdx.x;
  __shared__ float kp[13][3];
  if (t < 39) {
    float acc = bkps[t];
    const float* f = IF + (size_t)bn * 256;
    for (int d = 0; d < 256; ++d) acc = fmaf(f[d], Wkps[d * 39 + t], acc);
    int p = t / 3, ax = t % 3;
    kp[p][ax] = anchor[(size_t)bn * 256 + ax] + acc;
  }
  __syncthreads();
  if (t < 78) {
    int c = t / 13, p = t % 13;
    const float* M = projm + (size_t)(b * 6 + c) * 16;
    float kx = kp[p][0], ky = kp[p][1], kz = kp[p][2];
    float x = M[0] * kx + M[1] * ky + M[2] * kz + M[3];
    float y = M[4] * kx + M[5] * ky + M[6] * kz + M[7];
    float z = M[8] * kx + M[9] * ky + M[10] * kz + M[11];
    float zc = fmaxf(z, 1e-5f);
    float inv = 1.0f / zc;
    grid[(size_t)bn * 78 + t] = make_float2(x * inv, y * inv);
  }
}

// ---------------------------------------------------------------------------
// K3: aggregation v2.  Block per anchor (1800), 256 threads.
// Wave w (of 4) owns slots s ≡ w (mod 4); lane owns 4 channels (ushort4
// gathers, 8B/lane).  Per-corner wave-uniform skip of zero-weight corners.
// Cross-wave LDS reduction, then fused W_out matvec + bias + residual.
// MODE 0: bf16 NHWC ws.  MODE 1: f32 NCHW direct (fallback).
// ---------------------------------------------------------------------------
struct __align__(16) SlotInfo { int o[4]; float w[4]; };

template <int MODE>
__global__ __launch_bounds__(256) void dfa_agg(
    const __hip_bfloat16* __restrict__ fmws,
    const float* __restrict__ fm0, const float* __restrict__ fm1,
    const float* __restrict__ fm2, const float* __restrict__ fm3,
    const float2* __restrict__ grid, const float* __restrict__ wgt,
    const float* __restrict__ IF, const float* __restrict__ Wout,
    const float* __restrict__ bout, float* __restrict__ out) {
  int bn = blockIdx.x;
  int b = bn / C_NA;
  int t = threadIdx.x;
  int w = t >> 6, lane = t & 63;

  __shared__ SlotInfo slot[C_NSLOT];
  __shared__ int sflag[C_NSLOT];
  __shared__ float swgt[C_NCOL];
  __shared__ float part[4][256];
  __shared__ float fused[256];

  for (int i = t; i < C_NCOL; i += 256) swgt[i] = wgt[(size_t)bn * C_NCOL + i];

  for (int s = t; s < C_NSLOT; s += 256) {
    int c = s / 52, r = s % 52, l = r / 13, p = r % 13;
    float2 g2 = grid[(size_t)bn * 78 + c * 13 + p];
    int Wi = (l == 0) ? 176 : (l == 1) ? 88 : (l == 2) ? 44 : 22;
    int Hi = (l == 0) ? 64 : (l == 1) ? 32 : (l == 2) ? 16 : 8;
    float Wf = (float)Wi, Hf = (float)Hi;
    float ix = ((g2.x + 1.0f) * Wf - 1.0f) * 0.5f;
    float iy = ((g2.y + 1.0f) * Hf - 1.0f) * 0.5f;
    float ix0 = floorf(ix), iy0 = floorf(iy);
    float wx1 = ix - ix0, wy1 = iy - iy0;
    float wx0 = 1.f - wx1, wy0 = 1.f - wy1;
    bool vx0 = (ix0 >= 0.f) && (ix0 < Wf);
    bool vx1 = (ix0 + 1.f >= 0.f) && (ix0 + 1.f < Wf);
    bool vy0 = (iy0 >= 0.f) && (iy0 < Hf);
    bool vy1 = (iy0 + 1.f >= 0.f) && (iy0 + 1.f < Hf);
    int xi0 = (int)fminf(fmaxf(ix0, 0.f), Wf - 1.f);
    int xi1 = (int)fminf(fmaxf(ix0 + 1.f, 0.f), Wf - 1.f);
    int yi0 = (int)fminf(fmaxf(iy0, 0.f), Hf - 1.f);
    int yi1 = (int)fminf(fmaxf(iy0 + 1.f, 0.f), Hf - 1.f);
    float w00 = (vx0 && vy0) ? wy0 * wx0 : 0.f;
    float w01 = (vx1 && vy0) ? wy0 * wx1 : 0.f;
    float w10 = (vx0 && vy1) ? wy1 * wx0 : 0.f;
    float w11 = (vx1 && vy1) ? wy1 * wx1 : 0.f;
    int img = b * 6 + c;
    int HW = Wi * Hi;
    SlotInfo si;
    if (MODE == 0) {
      int lb = (l == 0) ? LB0 : (l == 1) ? LB1 : (l == 2) ? LB2 : LB3;
      int ib = lb + img * HW * 256;
      si.o[0] = ib + (yi0 * Wi + xi0) * 256;
      si.o[1] = ib + (yi0 * Wi + xi1) * 256;
      si.o[2] = ib + (yi1 * Wi + xi0) * 256;
      si.o[3] = ib + (yi1 * Wi + xi1) * 256;
    } else {
      int ib = img * 256 * HW;
      si.o[0] = ib + yi0 * Wi + xi0;
      si.o[1] = ib + yi0 * Wi + xi1;
      si.o[2] = ib + yi1 * Wi + xi0;
      si.o[3] = ib + yi1 * Wi + xi1;
    }
    si.w[0] = w00; si.w[1] = w01; si.w[2] = w10; si.w[3] = w11;
    slot[s] = si;
    sflag[s] = (w00 + w01 + w10 + w11 == 0.f) ? -1 : l;
  }
  __syncthreads();

  int g = lane >> 3;        // group of channel 4*lane
  int ch = lane * 4;
  float4 acc = make_float4(0.f, 0.f, 0.f, 0.f);
  for (int s = w; s < C_NSLOT; s += 4) {
    int fl = sflag[s];
    if (fl < 0) continue;   // uniform across wave
    SlotInfo si = slot[s];
    float wg = swgt[s * 8 + g];
    float4 sv = make_float4(0.f, 0.f, 0.f, 0.f);
    if (MODE == 0) {
#pragma unroll
      for (int k = 0; k < 4; ++k) {
        if (si.w[k] != 0.f) {   // wave-uniform -> s_cbranch_execz
          ushort4 u = *reinterpret_cast<const ushort4*>(
              reinterpret_cast<const unsigned short*>(fmws) + si.o[k] + ch);
          sv.x = fmaf(si.w[k], bf2f(u.x), sv.x);
          sv.y = fmaf(si.w[k], bf2f(u.y), sv.y);
          sv.z = fmaf(si.w[k], bf2f(u.z), sv.z);
          sv.w = fmaf(si.w[k], bf2f(u.w), sv.w);
        }
      }
    } else {
      const float* fp = (fl == 0) ? fm0 : (fl == 1) ? fm1 : (fl == 2) ? fm2 : fm3;
      int HW = (fl == 0) ? 11264 : (fl == 1) ? 2816 : (fl == 2) ? 704 : 176;
#pragma unroll
      for (int k = 0; k < 4; ++k) {
        if (si.w[k] != 0.f) {
          sv.x = fmaf(si.w[k], fp[si.o[k] + (size_t)(ch + 0) * HW], sv.x);
          sv.y = fmaf(si.w[k], fp[si.o[k] + (size_t)(ch + 1) * HW], sv.y);
          sv.z = fmaf(si.w[k], fp[si.o[k] + (size_t)(ch + 2) * HW], sv.z);
          sv.w = fmaf(si.w[k], fp[si.o[k] + (size_t)(ch + 3) * HW], sv.w);
        }
      }
    }
    acc.x = fmaf(sv.x, wg, acc.x);
    acc.y = fmaf(sv.y, wg, acc.y);
    acc.z = fmaf(sv.z, wg, acc.z);
    acc.w = fmaf(sv.w, wg, acc.w);
  }
  *reinterpret_cast<float4*>(&part[w][ch]) = acc;
  __syncthreads();

  fused[t] = part[0][t] + part[1][t] + part[2][t] + part[3][t];
  __syncthreads();

  float o = bout[t] + IF[(size_t)bn * 256 + t];
#pragma unroll 4
  for (int d = 0; d < 256; ++d)
    o = fmaf(fused[d], Wout[d * 256 + t], o);
  out[(size_t)bn * 256 + t] = o;
}

// ---------------------------------------------------------------------------
extern "C" void kernel_launch(void* const* d_in, const int* in_sizes, int n_in,
                              void* d_out, int out_size, void* d_ws, size_t ws_size,
                              hipStream_t stream) {
  const float* IF     = (const float*)d_in[0];
  const float* anchor = (const float*)d_in[1];
  const float* AE     = (const float*)d_in[2];
  const float* fm0    = (const float*)d_in[3];
  const float* fm1    = (const float*)d_in[4];
  const float* fm2    = (const float*)d_in[5];
  const float* fm3    = (const float*)d_in[6];
  const float* projm  = (const float*)d_in[7];
  const float* Wkps   = (const float*)d_in[8];
  const float* bkps   = (const float*)d_in[9];
  const float* Wwfc   = (const float*)d_in[10];
  const float* bwfc   = (const float*)d_in[11];
  const float* Wout   = (const float*)d_in[12];
  const float* bout   = (const float*)d_in[13];
  float* out = (float*)d_out;
  char* ws = (char*)d_ws;

  bool full = ws_size >= (FM_WS_BYTES + WGT_WS_BYTES + GRID_WS_BYTES);
  if (full) {
    __hip_bfloat16* fmws = (__hip_bfloat16*)ws;
    float* wgt  = (float*)(ws + FM_WS_BYTES);
    float2* grd = (float2*)(ws + FM_WS_BYTES + WGT_WS_BYTES);
    dfa_transpose<<<11232, 256, 0, stream>>>(fm0, fm1, fm2, fm3, fmws);
    dfa_logits_gemm<<<dim3(120, 10), 256, 0, stream>>>(IF, AE, Wwfc, bwfc, wgt);
    dfa_softmax<<<1800, 256, 0, stream>>>(wgt);
    dfa_points<<<1800, 128, 0, stream>>>(IF, anchor, Wkps, bkps, projm, grd);
    dfa_agg<0><<<1800, 256, 0, stream>>>(fmws, fm0, fm1, fm2, fm3, grd, wgt,
                                         IF, Wout, bout, out);
  } else {
    float* wgt  = (float*)ws;
    float2* grd = (float2*)(ws + WGT_WS_BYTES);
    dfa_logits_gemm<<<dim3(120, 10), 256, 0, stream>>>(IF, AE, Wwfc, bwfc, wgt);
    dfa_softmax<<<1800, 256, 0, stream>>>(wgt);
    dfa_points<<<1800, 128, 0, stream>>>(IF, anchor, Wkps, bkps, projm, grd);
    dfa_agg<1><<<1800, 256, 0, stream>>>(nullptr, fm0, fm1, fm2, fm3, grd, wgt,
                                         IF, Wout, bout, out);
  }
}

// Round 4
// 174.015 us; speedup vs baseline: 3.2602x; 1.5434x over previous
//
#include <hip/hip_runtime.h>
#include <hip/hip_bf16.h>

// Problem constants
#define C_NUM_CAMS 6
#define C_NUM_LEVELS 4
#define C_NUM_PTS 13
#define C_NUM_GROUPS 8
#define C_BS 2
#define C_NA 900
#define C_E 256
#define C_NSLOT 312      // C*L*P
#define C_NCOL 2496      // NSLOT * G
#define C_NANCH 1800     // BS*NA

// Level geometry: H 64,32,16,8; W 176,88,44,22; HW 11264,2816,704,176
#define LB0 0
#define LB1 34603008     // 12*11264*256
#define LB2 43253760     // +12*2816*256
#define LB3 45416448     // +12*704*256
#define FM_WS_BYTES 91914240ull
#define WGT_WS_BYTES 17971200ull   // 1800*2496*4
#define GRID_WS_BYTES 1123200ull   // 1800*78*8

static __device__ __forceinline__ unsigned short f2bf(float f) {
  __hip_bfloat16 h = __float2bfloat16(f);
  return *reinterpret_cast<unsigned short*>(&h);
}
static __device__ __forceinline__ float bf2f(unsigned short u) {
  unsigned int v = ((unsigned int)u) << 16;
  float f;
  __builtin_memcpy(&f, &v, 4);
  return f;
}
static __device__ __forceinline__ float lo16(int u) {
  unsigned int v = ((unsigned int)u) << 16;
  float f; __builtin_memcpy(&f, &v, 4); return f;
}
static __device__ __forceinline__ float hi16(int u) {
  unsigned int v = ((unsigned int)u) & 0xffff0000u;
  float f; __builtin_memcpy(&f, &v, 4); return f;
}

// ---------------------------------------------------------------------------
// K1: NCHW f32 -> NHWC bf16 transpose of all 4 feature maps into ws
// ---------------------------------------------------------------------------
__global__ __launch_bounds__(256) void dfa_transpose(
    const float* __restrict__ fm0, const float* __restrict__ fm1,
    const float* __restrict__ fm2, const float* __restrict__ fm3,
    __hip_bfloat16* __restrict__ out) {
  int id = blockIdx.x;
  const float* fm;
  int HW, ptiles;
  long long base;
  int rem;
  if (id < 8448)       { rem = id;         fm = fm0; HW = 11264; ptiles = 176; base = LB0; }
  else if (id < 10560) { rem = id - 8448;  fm = fm1; HW = 2816;  ptiles = 44;  base = LB1; }
  else if (id < 11088) { rem = id - 10560; fm = fm2; HW = 704;   ptiles = 11;  base = LB2; }
  else                 { rem = id - 11088; fm = fm3; HW = 176;   ptiles = 3;   base = LB3; }
  int img = rem / (ptiles * 4);
  int r2  = rem % (ptiles * 4);
  int ct  = r2 / ptiles;
  int pt  = r2 % ptiles;
  int c0 = ct * 64, pix0 = pt * 64;

  __shared__ float tile[64][65];
  int t = threadIdx.x;
  int tx = t & 63, ty = t >> 6;

  const float* src = fm + (size_t)(img * 256 + c0) * HW + pix0;
  if (pix0 + tx < HW) {
#pragma unroll
    for (int r = 0; r < 16; ++r) {
      int cl = r * 4 + ty;
      tile[cl][tx] = src[(size_t)cl * HW + tx];
    }
  }
  __syncthreads();
  int cx2 = (t & 31) * 2;
  int py8 = t >> 5;
  __hip_bfloat16* dst = out + base + ((long long)img * HW + pix0) * 256 + c0;
#pragma unroll
  for (int r = 0; r < 8; ++r) {
    int pl = r * 8 + py8;
    if (pix0 + pl < HW) {
      ushort2 u;
      u.x = f2bf(tile[cx2][pl]);
      u.y = f2bf(tile[cx2 + 1][pl]);
      *reinterpret_cast<ushort2*>(&dst[(long long)pl * 256 + cx2]) = u;
    }
  }
}

// ---------------------------------------------------------------------------
// K2: fusion-weight logits GEMM (raw logits; softmax fused into dfa_agg)
// ---------------------------------------------------------------------------
__global__ __launch_bounds__(256) void dfa_logits_gemm(
    const float* __restrict__ IF, const float* __restrict__ AE,
    const float* __restrict__ Wwfc, const float* __restrict__ bwfc,
    float* __restrict__ logits) {
  __shared__ float feat_t[256][16];   // [d][a], a<15 valid
  int t = threadIdx.x;
  int a0 = blockIdx.x * 15;
  int col = blockIdx.y * 256 + t;
  bool cv = col < C_NCOL;

#pragma unroll
  for (int a = 0; a < 15; ++a) {
    int bn = a0 + a;
    feat_t[t][a] = IF[(size_t)bn * 256 + t] + AE[(size_t)bn * 256 + t];
  }
  feat_t[t][15] = 0.f;
  __syncthreads();

  float acc[15];
  float bias = cv ? bwfc[col] : 0.f;
#pragma unroll
  for (int a = 0; a < 15; ++a) acc[a] = bias;

  const float* wp = Wwfc + col;
#pragma unroll 8
  for (int d = 0; d < 256; ++d) {
    float wv = cv ? wp[(size_t)d * C_NCOL] : 0.f;
    float4 f0 = *(const float4*)&feat_t[d][0];
    float4 f1 = *(const float4*)&feat_t[d][4];
    float4 f2 = *(const float4*)&feat_t[d][8];
    float4 f3 = *(const float4*)&feat_t[d][12];
    acc[0]  = fmaf(f0.x, wv, acc[0]);
    acc[1]  = fmaf(f0.y, wv, acc[1]);
    acc[2]  = fmaf(f0.z, wv, acc[2]);
    acc[3]  = fmaf(f0.w, wv, acc[3]);
    acc[4]  = fmaf(f1.x, wv, acc[4]);
    acc[5]  = fmaf(f1.y, wv, acc[5]);
    acc[6]  = fmaf(f1.z, wv, acc[6]);
    acc[7]  = fmaf(f1.w, wv, acc[7]);
    acc[8]  = fmaf(f2.x, wv, acc[8]);
    acc[9]  = fmaf(f2.y, wv, acc[9]);
    acc[10] = fmaf(f2.z, wv, acc[10]);
    acc[11] = fmaf(f2.w, wv, acc[11]);
    acc[12] = fmaf(f3.x, wv, acc[12]);
    acc[13] = fmaf(f3.y, wv, acc[13]);
    acc[14] = fmaf(f3.z, wv, acc[14]);
  }

  if (cv) {
#pragma unroll
    for (int a = 0; a < 15; ++a)
      logits[(size_t)(a0 + a) * C_NCOL + col] = acc[a];
  }
}

// ---------------------------------------------------------------------------
// K3: fused aggregation.  Block per anchor (1800), 256 threads, 4 waves.
// In-block: softmax(logits) -> bf16 LDS; keypoints+projection; per-wave
// per-lane slot geometry + ballot-compacted corner list (branch-free main
// loop, lanes split in half over corner pairs, int4 = 8 bf16 ch per lane);
// cross-wave reduce; fused W_out matvec + bias + residual.
// ---------------------------------------------------------------------------
__global__ __launch_bounds__(256) void dfa_agg_full(
    const __hip_bfloat16* __restrict__ fmws,
    const float* __restrict__ logits,
    const float* __restrict__ IF, const float* __restrict__ anchor,
    const float* __restrict__ Wkps, const float* __restrict__ bkps,
    const float* __restrict__ projm,
    const float* __restrict__ Wout, const float* __restrict__ bout,
    float* __restrict__ out) {
  int bn = blockIdx.x;
  int b = bn / C_NA;
  int t = threadIdx.x;
  int w = t >> 6, lane = t & 63;

  // regionX: logits f32[2496] -> corner entries int2[1248] (per-wave segments)
  __shared__ __align__(16) char regionX[9984];
  __shared__ __align__(16) float partS[8][256];       // also fresh scratch
  __shared__ unsigned short swgt_bf[C_NCOL];
  __shared__ unsigned short csS[1248];
  __shared__ __align__(16) float fusedS[256];         // doubles as grid f2[78]
  __shared__ float kpS[13][3];
  __shared__ float invS[8];

  float* logitsS = (float*)regionX;
  int2* centry = (int2*)regionX;
  float2* gridS = (float2*)fusedS;

  // --- phase 1: load raw logits (float4) ---
  {
    float4* dst4 = (float4*)logitsS;
    const float4* src4 = (const float4*)(logits + (size_t)bn * C_NCOL);
    for (int i = t; i < C_NCOL / 4; i += 256) dst4[i] = src4[i];
  }
  __syncthreads();

  // --- phase 2: softmax over 312 slots per group (8 groups x 32 lanes) ---
  {
    int g = t >> 5, l32 = t & 31;
    float m = -1e30f;
    for (int s = l32; s < C_NSLOT; s += 32) m = fmaxf(m, logitsS[s * 8 + g]);
#pragma unroll
    for (int off = 16; off; off >>= 1) m = fmaxf(m, __shfl_xor(m, off, 32));
    float sum = 0.f;
    for (int s = l32; s < C_NSLOT; s += 32) {
      float e = __expf(logitsS[s * 8 + g] - m);
      logitsS[s * 8 + g] = e;
      sum += e;
    }
#pragma unroll
    for (int off = 16; off; off >>= 1) sum += __shfl_xor(sum, off, 32);
    if (l32 == 0) invS[g] = 1.f / sum;
  }
  __syncthreads();

  // --- phase 3: normalize -> bf16 swgt; keypoints matvec (t<39) ---
  for (int i = t; i < C_NCOL; i += 256)
    swgt_bf[i] = f2bf(logitsS[i] * invS[i & 7]);
  if (t < 39) {
    const float* f = IF + (size_t)bn * 256;
    float a0 = 0.f, a1 = 0.f, a2 = 0.f, a3 = 0.f;
    for (int d = 0; d < 256; d += 4) {
      a0 = fmaf(f[d + 0], Wkps[(d + 0) * 39 + t], a0);
      a1 = fmaf(f[d + 1], Wkps[(d + 1) * 39 + t], a1);
      a2 = fmaf(f[d + 2], Wkps[(d + 2) * 39 + t], a2);
      a3 = fmaf(f[d + 3], Wkps[(d + 3) * 39 + t], a3);
    }
    float acc = bkps[t] + ((a0 + a1) + (a2 + a3));
    int p = t / 3, ax = t % 3;
    kpS[p][ax] = anchor[(size_t)bn * 256 + ax] + acc;
  }
  __syncthreads();

  // --- phase 4: projection (t<78) -> gridS ---
  if (t < 78) {
    int c = t / 13, p = t % 13;
    const float* M = projm + (size_t)(b * 6 + c) * 16;
    float kx = kpS[p][0], ky = kpS[p][1], kz = kpS[p][2];
    float x = M[0] * kx + M[1] * ky + M[2] * kz + M[3];
    float y = M[4] * kx + M[5] * ky + M[6] * kz + M[7];
    float z = M[8] * kx + M[9] * ky + M[10] * kz + M[11];
    float zc = fmaxf(z, 1e-5f);
    float inv = 1.0f / zc;
    gridS[t] = make_float2(x * inv, y * inv);
  }
  __syncthreads();

  // --- phase 5: per-wave slot geometry + ballot corner compaction ---
  // wave w owns slots [w*78, (w+1)*78); appends valid corners to its own
  // 312-entry segment of centry/csS.  Deterministic order.
  int cnt = 0;
  {
    int ebase = w * 312;
#pragma unroll
    for (int r = 0; r < 2; ++r) {
      int li = r * 64 + lane;
      bool lv = li < 78;
      int s = w * 78 + (lv ? li : 0);
      int cam = s / 52, rr = s % 52, l = rr / 13, p = rr % 13;
      float2 g2 = gridS[cam * 13 + p];
      int Wi = (l == 0) ? 176 : (l == 1) ? 88 : (l == 2) ? 44 : 22;
      int Hi = (l == 0) ? 64 : (l == 1) ? 32 : (l == 2) ? 16 : 8;
      float Wf = (float)Wi, Hf = (float)Hi;
      float ix = ((g2.x + 1.0f) * Wf - 1.0f) * 0.5f;
      float iy = ((g2.y + 1.0f) * Hf - 1.0f) * 0.5f;
      float ix0 = floorf(ix), iy0 = floorf(iy);
      float wx1 = ix - ix0, wy1 = iy - iy0;
      float wx0 = 1.f - wx1, wy0 = 1.f - wy1;
      bool vx0 = (ix0 >= 0.f) && (ix0 < Wf);
      bool vx1 = (ix0 + 1.f >= 0.f) && (ix0 + 1.f < Wf);
      bool vy0 = (iy0 >= 0.f) && (iy0 < Hf);
      bool vy1 = (iy0 + 1.f >= 0.f) && (iy0 + 1.f < Hf);
      int xi0 = (int)fminf(fmaxf(ix0, 0.f), Wf - 1.f);
      int xi1 = (int)fminf(fmaxf(ix0 + 1.f, 0.f), Wf - 1.f);
      int yi0 = (int)fminf(fmaxf(iy0, 0.f), Hf - 1.f);
      int yi1 = (int)fminf(fmaxf(iy0 + 1.f, 0.f), Hf - 1.f);
      int lb = (l == 0) ? LB0 : (l == 1) ? LB1 : (l == 2) ? LB2 : LB3;
      int ib = lb + (b * 6 + cam) * Wi * Hi * 256;
      float cw[4];
      int co[4];
      cw[0] = (vx0 && vy0) ? wy0 * wx0 : 0.f;
      cw[1] = (vx1 && vy0) ? wy0 * wx1 : 0.f;
      cw[2] = (vx0 && vy1) ? wy1 * wx0 : 0.f;
      cw[3] = (vx1 && vy1) ? wy1 * wx1 : 0.f;
      co[0] = ib + (yi0 * Wi + xi0) * 256;
      co[1] = ib + (yi0 * Wi + xi1) * 256;
      co[2] = ib + (yi1 * Wi + xi0) * 256;
      co[3] = ib + (yi1 * Wi + xi1) * 256;
      unsigned short sw8 = (unsigned short)(s * 8);
#pragma unroll
      for (int k = 0; k < 4; ++k) {
        bool v = lv && (cw[k] != 0.f);
        unsigned long long mb = __ballot(v);
        int pos = cnt + __popcll(mb & ((1ull << lane) - 1ull));
        if (v) {
          centry[ebase + pos] = make_int2(co[k], __float_as_int(cw[k]));
          csS[ebase + pos] = sw8;
        }
        cnt += (int)__popcll(mb);
      }
    }
    if (cnt & 1) {
      if (lane == 0) {
        centry[ebase + cnt] = make_int2(0, 0);
        csS[ebase + cnt] = 0;
      }
      cnt++;
    }
  }
  // no barrier needed: each wave reads only its own segment below

  // --- phase 6: branch-free gather main loop ---
  int half = lane >> 5, l32 = lane & 31;
  int ch = l32 * 8;
  int g = l32 >> 2;
  float acc[8];
#pragma unroll
  for (int j = 0; j < 8; ++j) acc[j] = 0.f;
  {
    int ebase = w * 312;
    int nIter = cnt >> 1;
    const unsigned short* fmu = (const unsigned short*)fmws;
#pragma unroll 4
    for (int i = 0; i < nIter; ++i) {
      int idx = ebase + 2 * i + half;
      int2 e = centry[idx];
      int swi = (int)csS[idx] + g;
      float wgt_s = bf2f(swgt_bf[swi]);
      float cw = __int_as_float(e.y) * wgt_s;
      int4 u = *reinterpret_cast<const int4*>(fmu + e.x + ch);
      acc[0] = fmaf(cw, lo16(u.x), acc[0]);
      acc[1] = fmaf(cw, hi16(u.x), acc[1]);
      acc[2] = fmaf(cw, lo16(u.y), acc[2]);
      acc[3] = fmaf(cw, hi16(u.y), acc[3]);
      acc[4] = fmaf(cw, lo16(u.z), acc[4]);
      acc[5] = fmaf(cw, hi16(u.z), acc[5]);
      acc[6] = fmaf(cw, lo16(u.w), acc[6]);
      acc[7] = fmaf(cw, hi16(u.w), acc[7]);
    }
  }
  {
    int row = w * 2 + half;
    float4 v0 = make_float4(acc[0], acc[1], acc[2], acc[3]);
    float4 v1 = make_float4(acc[4], acc[5], acc[6], acc[7]);
    *reinterpret_cast<float4*>(&partS[row][ch]) = v0;
    *reinterpret_cast<float4*>(&partS[row][ch + 4]) = v1;
  }
  __syncthreads();

  // --- phase 7: cross-wave reduce + fused W_out epilogue ---
  float fv = 0.f;
#pragma unroll
  for (int r = 0; r < 8; ++r) fv += partS[r][t];
  fusedS[t] = fv;
  __syncthreads();

  float o = bout[t] + IF[(size_t)bn * 256 + t];
#pragma unroll 8
  for (int d = 0; d < 256; ++d)
    o = fmaf(fusedS[d], Wout[d * 256 + t], o);
  out[(size_t)bn * 256 + t] = o;
}

// ---------------------------------------------------------------------------
// Fallback path (small ws): old softmax/points/agg on NCHW f32 directly
// ---------------------------------------------------------------------------
__global__ __launch_bounds__(256) void dfa_softmax(float* __restrict__ wgt) {
  int bn = blockIdx.x;
  float* w = wgt + (size_t)bn * C_NCOL;
  __shared__ float buf[C_NCOL];
  int t = threadIdx.x;
  for (int i = t; i < C_NCOL; i += 256) buf[i] = w[i];
  __syncthreads();
  int g = t >> 5, lane = t & 31;
  float m = -1e30f;
  for (int s = lane; s < C_NSLOT; s += 32) m = fmaxf(m, buf[s * 8 + g]);
#pragma unroll
  for (int off = 16; off; off >>= 1) m = fmaxf(m, __shfl_xor(m, off, 32));
  float sum = 0.f;
  for (int s = lane; s < C_NSLOT; s += 32) {
    float e = expf(buf[s * 8 + g] - m);
    buf[s * 8 + g] = e;
    sum += e;
  }
#pragma unroll
  for (int off = 16; off; off >>= 1) sum += __shfl_xor(sum, off, 32);
  float inv = 1.f / sum;
  for (int s = lane; s < C_NSLOT; s += 32) w[s * 8 + g] = buf[s * 8 + g] * inv;
}

__global__ __launch_bounds__(128) void dfa_points(
    const float* __restrict__ IF, const float* __restrict__ anchor,
    const float* __restrict__ Wkps, const float* __restrict__ bkps,
    const float* __restrict__ projm, float2* __restrict__ grid) {
  int bn = blockIdx.x;
  int b = bn / C_NA;
  int t = threadIdx.x;
  __shared__ float kp[13][3];
  if (t < 39) {
    float acc = bkps[t];
    const float* f = IF + (size_t)bn * 256;
    for (int d = 0; d < 256; ++d) acc = fmaf(f[d], Wkps[d * 39 + t], acc);
    int p = t / 3, ax = t % 3;
    kp[p][ax] = anchor[(size_t)bn * 256 + ax] + acc;
  }
  __syncthreads();
  if (t < 78) {
    int c = t / 13, p = t % 13;
    const float* M = projm + (size_t)(b * 6 + c) * 16;
    float kx = kp[p][0], ky = kp[p][1], kz = kp[p][2];
    float x = M[0] * kx + M[1] * ky + M[2] * kz + M[3];
    float y = M[4] * kx + M[5] * ky + M[6] * kz + M[7];
    float z = M[8] * kx + M[9] * ky + M[10] * kz + M[11];
    float zc = fmaxf(z, 1e-5f);
    float inv = 1.0f / zc;
    grid[(size_t)bn * 78 + t] = make_float2(x * inv, y * inv);
  }
}

struct __align__(16) SlotInfo { int o[4]; float w[4]; };

__global__ __launch_bounds__(256) void dfa_agg_fb(
    const float* __restrict__ fm0, const float* __restrict__ fm1,
    const float* __restrict__ fm2, const float* __restrict__ fm3,
    const float2* __restrict__ grid, const float* __restrict__ wgt,
    const float* __restrict__ IF, const float* __restrict__ Wout,
    const float* __restrict__ bout, float* __restrict__ out) {
  int bn = blockIdx.x;
  int b = bn / C_NA;
  int t = threadIdx.x;
  int w = t >> 6, lane = t & 63;

  __shared__ SlotInfo slot[C_NSLOT];
  __shared__ int sflag[C_NSLOT];
  __shared__ float swgt[C_NCOL];
  __shared__ float part[4][256];
  __shared__ float fused[256];

  for (int i = t; i < C_NCOL; i += 256) swgt[i] = wgt[(size_t)bn * C_NCOL + i];

  for (int s = t; s < C_NSLOT; s += 256) {
    int c = s / 52, r = s % 52, l = r / 13, p = r % 13;
    float2 g2 = grid[(size_t)bn * 78 + c * 13 + p];
    int Wi = (l == 0) ? 176 : (l == 1) ? 88 : (l == 2) ? 44 : 22;
    int Hi = (l == 0) ? 64 : (l == 1) ? 32 : (l == 2) ? 16 : 8;
    float Wf = (float)Wi, Hf = (float)Hi;
    float ix = ((g2.x + 1.0f) * Wf - 1.0f) * 0.5f;
    float iy = ((g2.y + 1.0f) * Hf - 1.0f) * 0.5f;
    float ix0 = floorf(ix), iy0 = floorf(iy);
    float wx1 = ix - ix0, wy1 = iy - iy0;
    float wx0 = 1.f - wx1, wy0 = 1.f - wy1;
    bool vx0 = (ix0 >= 0.f) && (ix0 < Wf);
    bool vx1 = (ix0 + 1.f >= 0.f) && (ix0 + 1.f < Wf);
    bool vy0 = (iy0 >= 0.f) && (iy0 < Hf);
    bool vy1 = (iy0 + 1.f >= 0.f) && (iy0 + 1.f < Hf);
    int xi0 = (int)fminf(fmaxf(ix0, 0.f), Wf - 1.f);
    int xi1 = (int)fminf(fmaxf(ix0 + 1.f, 0.f), Wf - 1.f);
    int yi0 = (int)fminf(fmaxf(iy0, 0.f), Hf - 1.f);
    int yi1 = (int)fminf(fmaxf(iy0 + 1.f, 0.f), Hf - 1.f);
    int img = b * 6 + c;
    int HW = Wi * Hi;
    SlotInfo si;
    int ib = img * 256 * HW;
    si.o[0] = ib + yi0 * Wi + xi0;
    si.o[1] = ib + yi0 * Wi + xi1;
    si.o[2] = ib + yi1 * Wi + xi0;
    si.o[3] = ib + yi1 * Wi + xi1;
    si.w[0] = (vx0 && vy0) ? wy0 * wx0 : 0.f;
    si.w[1] = (vx1 && vy0) ? wy0 * wx1 : 0.f;
    si.w[2] = (vx0 && vy1) ? wy1 * wx0 : 0.f;
    si.w[3] = (vx1 && vy1) ? wy1 * wx1 : 0.f;
    slot[s] = si;
    sflag[s] = (si.w[0] + si.w[1] + si.w[2] + si.w[3] == 0.f) ? -1 : l;
  }
  __syncthreads();

  int g = lane >> 3;
  int ch = lane * 4;
  float4 acc = make_float4(0.f, 0.f, 0.f, 0.f);
  for (int s = w; s < C_NSLOT; s += 4) {
    int fl = sflag[s];
    if (fl < 0) continue;
    SlotInfo si = slot[s];
    float wg = swgt[s * 8 + g];
    const float* fp = (fl == 0) ? fm0 : (fl == 1) ? fm1 : (fl == 2) ? fm2 : fm3;
    int HW = (fl == 0) ? 11264 : (fl == 1) ? 2816 : (fl == 2) ? 704 : 176;
    float4 sv = make_float4(0.f, 0.f, 0.f, 0.f);
#pragma unroll
    for (int k = 0; k < 4; ++k) {
      if (si.w[k] != 0.f) {
        sv.x = fmaf(si.w[k], fp[si.o[k] + (size_t)(ch + 0) * HW], sv.x);
        sv.y = fmaf(si.w[k], fp[si.o[k] + (size_t)(ch + 1) * HW], sv.y);
        sv.z = fmaf(si.w[k], fp[si.o[k] + (size_t)(ch + 2) * HW], sv.z);
        sv.w = fmaf(si.w[k], fp[si.o[k] + (size_t)(ch + 3) * HW], sv.w);
      }
    }
    acc.x = fmaf(sv.x, wg, acc.x);
    acc.y = fmaf(sv.y, wg, acc.y);
    acc.z = fmaf(sv.z, wg, acc.z);
    acc.w = fmaf(sv.w, wg, acc.w);
  }
  *reinterpret_cast<float4*>(&part[w][ch]) = acc;
  __syncthreads();

  fused[t] = part[0][t] + part[1][t] + part[2][t] + part[3][t];
  __syncthreads();

  float o = bout[t] + IF[(size_t)bn * 256 + t];
#pragma unroll 4
  for (int d = 0; d < 256; ++d)
    o = fmaf(fused[d], Wout[d * 256 + t], o);
  out[(size_t)bn * 256 + t] = o;
}

// ---------------------------------------------------------------------------
extern "C" void kernel_launch(void* const* d_in, const int* in_sizes, int n_in,
                              void* d_out, int out_size, void* d_ws, size_t ws_size,
                              hipStream_t stream) {
  const float* IF     = (const float*)d_in[0];
  const float* anchor = (const float*)d_in[1];
  const float* AE     = (const float*)d_in[2];
  const float* fm0    = (const float*)d_in[3];
  const float* fm1    = (const float*)d_in[4];
  const float* fm2    = (const float*)d_in[5];
  const float* fm3    = (const float*)d_in[6];
  const float* projm  = (const float*)d_in[7];
  const float* Wkps   = (const float*)d_in[8];
  const float* bkps   = (const float*)d_in[9];
  const float* Wwfc   = (const float*)d_in[10];
  const float* bwfc   = (const float*)d_in[11];
  const float* Wout   = (const float*)d_in[12];
  const float* bout   = (const float*)d_in[13];
  float* out = (float*)d_out;
  char* ws = (char*)d_ws;

  bool full = ws_size >= (FM_WS_BYTES + WGT_WS_BYTES + GRID_WS_BYTES);
  if (full) {
    __hip_bfloat16* fmws = (__hip_bfloat16*)ws;
    float* wgt  = (float*)(ws + FM_WS_BYTES);
    dfa_transpose<<<11232, 256, 0, stream>>>(fm0, fm1, fm2, fm3, fmws);
    dfa_logits_gemm<<<dim3(120, 10), 256, 0, stream>>>(IF, AE, Wwfc, bwfc, wgt);
    dfa_agg_full<<<1800, 256, 0, stream>>>(fmws, wgt, IF, anchor, Wkps, bkps,
                                           projm, Wout, bout, out);
  } else {
    float* wgt  = (float*)ws;
    float2* grd = (float2*)(ws + WGT_WS_BYTES);
    dfa_logits_gemm<<<dim3(120, 10), 256, 0, stream>>>(IF, AE, Wwfc, bwfc, wgt);
    dfa_softmax<<<1800, 256, 0, stream>>>(wgt);
    dfa_points<<<1800, 128, 0, stream>>>(IF, anchor, Wkps, bkps, projm, grd);
    dfa_agg_fb<<<1800, 256, 0, stream>>>(fm0, fm1, fm2, fm3, grd, wgt,
                                         IF, Wout, bout, out);
  }
}

// Round 5
// 153.653 us; speedup vs baseline: 3.6923x; 1.1325x over previous
//
#include <hip/hip_runtime.h>
#include <hip/hip_bf16.h>

// Problem constants
#define C_NUM_CAMS 6
#define C_NUM_LEVELS 4
#define C_NUM_PTS 13
#define C_NUM_GROUPS 8
#define C_BS 2
#define C_NA 900
#define C_E 256
#define C_NSLOT 312      // C*L*P
#define C_NCOL 2496      // NSLOT * G
#define C_NANCH 1800     // BS*NA

// Level geometry: H 64,32,16,8; W 176,88,44,22; HW 11264,2816,704,176
// fp8 ws: 1 byte/elem, bases in bytes
#define LB0 0
#define LB1 34603008     // 12*11264*256
#define LB2 43253760     // +12*2816*256
#define LB3 45416448     // +12*704*256
#define FM8_WS_BYTES 45957120ull
#define WGT_WS_BYTES 17971200ull   // 1800*2496*4
#define GRID_WS_BYTES 1123200ull   // 1800*78*8

typedef float floatx2 __attribute__((ext_vector_type(2)));

static __device__ __forceinline__ int pk_fp8(float a, float b, float c, float d) {
  int v = __builtin_amdgcn_cvt_pk_fp8_f32(a, b, 0, false);   // bytes 0,1
  v = __builtin_amdgcn_cvt_pk_fp8_f32(c, d, v, true);        // bytes 2,3
  return v;
}

// ---------------------------------------------------------------------------
// K1: heterogeneous stage-1 kernel.
//   blocks [0, 11232): NCHW f32 -> NHWC fp8(e4m3) transpose of all 4 fms
//   blocks [11232, 12432): fusion-weight logits GEMM (15 anchors x 256 cols)
// ---------------------------------------------------------------------------
__global__ __launch_bounds__(256) void dfa_stage1(
    const float* __restrict__ fm0, const float* __restrict__ fm1,
    const float* __restrict__ fm2, const float* __restrict__ fm3,
    unsigned char* __restrict__ fmws,
    const float* __restrict__ IF, const float* __restrict__ AE,
    const float* __restrict__ Wwfc, const float* __restrict__ bwfc,
    float* __restrict__ logits) {
  __shared__ __align__(16) float smem[64 * 65];   // 16.6 KB, aliased per path
  int id = blockIdx.x;
  int t = threadIdx.x;

  if (id < 11232) {
    // ---------------- transpose path ----------------
    const float* fm;
    int HW, ptiles;
    long long base;
    int rem;
    if (id < 8448)       { rem = id;         fm = fm0; HW = 11264; ptiles = 176; base = LB0; }
    else if (id < 10560) { rem = id - 8448;  fm = fm1; HW = 2816;  ptiles = 44;  base = LB1; }
    else if (id < 11088) { rem = id - 10560; fm = fm2; HW = 704;   ptiles = 11;  base = LB2; }
    else                 { rem = id - 11088; fm = fm3; HW = 176;   ptiles = 3;   base = LB3; }
    int img = rem / (ptiles * 4);
    int r2  = rem % (ptiles * 4);
    int ct  = r2 / ptiles;
    int pt  = r2 % ptiles;
    int c0 = ct * 64, pix0 = pt * 64;

    float (*tile)[65] = (float(*)[65])smem;

    // read: 4 iters of float4 (16 ch x 64 pix per iter)
#pragma unroll
    for (int i = 0; i < 4; ++i) {
      int ch = i * 16 + (t >> 4);
      int px = (t & 15) * 4;
      if (pix0 + px < HW) {
        float4 v = *(const float4*)(fm + (size_t)(img * 256 + c0 + ch) * HW + pix0 + px);
        tile[ch][px + 0] = v.x;
        tile[ch][px + 1] = v.y;
        tile[ch][px + 2] = v.z;
        tile[ch][px + 3] = v.w;
      }
    }
    __syncthreads();

    // write: lane packs 16 consecutive channels of one pixel -> int4 (16B)
    int p = t >> 2, ch0 = (t & 3) * 16;
    if (pix0 + p < HW) {
      int4 o;
      o.x = pk_fp8(tile[ch0 + 0][p],  tile[ch0 + 1][p],  tile[ch0 + 2][p],  tile[ch0 + 3][p]);
      o.y = pk_fp8(tile[ch0 + 4][p],  tile[ch0 + 5][p],  tile[ch0 + 6][p],  tile[ch0 + 7][p]);
      o.z = pk_fp8(tile[ch0 + 8][p],  tile[ch0 + 9][p],  tile[ch0 + 10][p], tile[ch0 + 11][p]);
      o.w = pk_fp8(tile[ch0 + 12][p], tile[ch0 + 13][p], tile[ch0 + 14][p], tile[ch0 + 15][p]);
      *(int4*)(fmws + base + ((long long)img * HW + pix0 + p) * 256 + c0 + ch0) = o;
    }
  } else {
    // ---------------- logits GEMM path ----------------
    float (*feat_t)[16] = (float(*)[16])smem;   // [d][a], 4096 floats
    int rem = id - 11232;
    int a0 = (rem % 120) * 15;
    int col = (rem / 120) * 256 + t;
    bool cv = col < C_NCOL;

#pragma unroll
    for (int a = 0; a < 15; ++a) {
      int bn = a0 + a;
      feat_t[t][a] = IF[(size_t)bn * 256 + t] + AE[(size_t)bn * 256 + t];
    }
    feat_t[t][15] = 0.f;
    __syncthreads();

    float acc[15];
    float bias = cv ? bwfc[col] : 0.f;
#pragma unroll
    for (int a = 0; a < 15; ++a) acc[a] = bias;

    const float* wp = Wwfc + col;
#pragma unroll 8
    for (int d = 0; d < 256; ++d) {
      float wv = cv ? wp[(size_t)d * C_NCOL] : 0.f;
      float4 f0 = *(const float4*)&feat_t[d][0];
      float4 f1 = *(const float4*)&feat_t[d][4];
      float4 f2 = *(const float4*)&feat_t[d][8];
      float4 f3 = *(const float4*)&feat_t[d][12];
      acc[0]  = fmaf(f0.x, wv, acc[0]);
      acc[1]  = fmaf(f0.y, wv, acc[1]);
      acc[2]  = fmaf(f0.z, wv, acc[2]);
      acc[3]  = fmaf(f0.w, wv, acc[3]);
      acc[4]  = fmaf(f1.x, wv, acc[4]);
      acc[5]  = fmaf(f1.y, wv, acc[5]);
      acc[6]  = fmaf(f1.z, wv, acc[6]);
      acc[7]  = fmaf(f1.w, wv, acc[7]);
      acc[8]  = fmaf(f2.x, wv, acc[8]);
      acc[9]  = fmaf(f2.y, wv, acc[9]);
      acc[10] = fmaf(f2.z, wv, acc[10]);
      acc[11] = fmaf(f2.w, wv, acc[11]);
      acc[12] = fmaf(f3.x, wv, acc[12]);
      acc[13] = fmaf(f3.y, wv, acc[13]);
      acc[14] = fmaf(f3.z, wv, acc[14]);
    }

    if (cv) {
#pragma unroll
      for (int a = 0; a < 15; ++a)
        logits[(size_t)(a0 + a) * C_NCOL + col] = acc[a];
    }
  }
}

// ---------------------------------------------------------------------------
// K2: fused aggregation (fp8 ws).  Block per anchor (1800), 256 threads.
// softmax (logits in [g][s] LDS layout, conflict-free) -> f32 swgt;
// keypoints+projection; ballot-compacted corner list; branch-free gather of
// int2 = 8 fp8 channels/lane (256B/corner, HW fp8->f32 cvt); cross-wave
// reduce; fused W_out matvec + bias + residual.
// ---------------------------------------------------------------------------
__global__ __launch_bounds__(256) void dfa_agg_full(
    const unsigned char* __restrict__ fmws,
    const float* __restrict__ logits,
    const float* __restrict__ IF, const float* __restrict__ anchor,
    const float* __restrict__ Wkps, const float* __restrict__ bkps,
    const float* __restrict__ projm,
    const float* __restrict__ Wout, const float* __restrict__ bout,
    float* __restrict__ out) {
  int bn = blockIdx.x;
  int b = bn / C_NA;
  int t = threadIdx.x;
  int w = t >> 6, lane = t & 63;

  __shared__ __align__(16) float logitsS[8 * 312];    // [g][s]; reused as centry
  __shared__ __align__(16) float swgt[C_NCOL];
  __shared__ unsigned short csS[1248];
  __shared__ __align__(16) float partS[8][256];
  __shared__ __align__(16) float fusedS[256];         // doubles as grid f2[78]
  __shared__ float kpS[13][3];
  __shared__ float invS[8];

  int2* centry = (int2*)logitsS;                      // 1248 int2 = 9984 B
  float2* gridS = (float2*)fusedS;

  // --- phase 1: load logits, scatter to [g][s] ---
  for (int i = t; i < C_NCOL; i += 256) {
    float v = logits[(size_t)bn * C_NCOL + i];
    logitsS[(i & 7) * 312 + (i >> 3)] = v;
  }
  __syncthreads();

  // --- phase 2: softmax per group (8 groups x 32 lanes) ---
  {
    int g = t >> 5, l32 = t & 31;
    float* row = logitsS + g * 312;
    float m = -1e30f;
    for (int s = l32; s < C_NSLOT; s += 32) m = fmaxf(m, row[s]);
#pragma unroll
    for (int off = 16; off; off >>= 1) m = fmaxf(m, __shfl_xor(m, off, 32));
    float sum = 0.f;
    for (int s = l32; s < C_NSLOT; s += 32) {
      float e = __expf(row[s] - m);
      row[s] = e;
      sum += e;
    }
#pragma unroll
    for (int off = 16; off; off >>= 1) sum += __shfl_xor(sum, off, 32);
    if (l32 == 0) invS[g] = 1.f / sum;
  }
  __syncthreads();

  // --- phase 3: normalized f32 weights back to [s*8+g]; keypoints (t<39) ---
  for (int i = t; i < C_NCOL; i += 256)
    swgt[i] = logitsS[(i & 7) * 312 + (i >> 3)] * invS[i & 7];
  if (t < 39) {
    const float* f = IF + (size_t)bn * 256;
    float a0 = 0.f, a1 = 0.f, a2 = 0.f, a3 = 0.f;
    for (int d = 0; d < 256; d += 4) {
      a0 = fmaf(f[d + 0], Wkps[(d + 0) * 39 + t], a0);
      a1 = fmaf(f[d + 1], Wkps[(d + 1) * 39 + t], a1);
      a2 = fmaf(f[d + 2], Wkps[(d + 2) * 39 + t], a2);
      a3 = fmaf(f[d + 3], Wkps[(d + 3) * 39 + t], a3);
    }
    float acc = bkps[t] + ((a0 + a1) + (a2 + a3));
    int p = t / 3, ax = t % 3;
    kpS[p][ax] = anchor[(size_t)bn * 256 + ax] + acc;
  }
  __syncthreads();

  // --- phase 4: projection (t<78) -> gridS ---
  if (t < 78) {
    int c = t / 13, p = t % 13;
    const float* M = projm + (size_t)(b * 6 + c) * 16;
    float kx = kpS[p][0], ky = kpS[p][1], kz = kpS[p][2];
    float x = M[0] * kx + M[1] * ky + M[2] * kz + M[3];
    float y = M[4] * kx + M[5] * ky + M[6] * kz + M[7];
    float z = M[8] * kx + M[9] * ky + M[10] * kz + M[11];
    float zc = fmaxf(z, 1e-5f);
    float inv = 1.0f / zc;
    gridS[t] = make_float2(x * inv, y * inv);
  }
  __syncthreads();

  // --- phase 5: per-wave slot geometry + ballot corner compaction ---
  // (centry overlaps logitsS; all logitsS reads finished at phase 3 barrier)
  int cnt = 0;
  {
    int ebase = w * 312;
#pragma unroll
    for (int r = 0; r < 2; ++r) {
      int li = r * 64 + lane;
      bool lv = li < 78;
      int s = w * 78 + (lv ? li : 0);
      int cam = s / 52, rr = s % 52, l = rr / 13, p = rr % 13;
      float2 g2 = gridS[cam * 13 + p];
      int Wi = (l == 0) ? 176 : (l == 1) ? 88 : (l == 2) ? 44 : 22;
      int Hi = (l == 0) ? 64 : (l == 1) ? 32 : (l == 2) ? 16 : 8;
      float Wf = (float)Wi, Hf = (float)Hi;
      float ix = ((g2.x + 1.0f) * Wf - 1.0f) * 0.5f;
      float iy = ((g2.y + 1.0f) * Hf - 1.0f) * 0.5f;
      float ix0 = floorf(ix), iy0 = floorf(iy);
      float wx1 = ix - ix0, wy1 = iy - iy0;
      float wx0 = 1.f - wx1, wy0 = 1.f - wy1;
      bool vx0 = (ix0 >= 0.f) && (ix0 < Wf);
      bool vx1 = (ix0 + 1.f >= 0.f) && (ix0 + 1.f < Wf);
      bool vy0 = (iy0 >= 0.f) && (iy0 < Hf);
      bool vy1 = (iy0 + 1.f >= 0.f) && (iy0 + 1.f < Hf);
      int xi0 = (int)fminf(fmaxf(ix0, 0.f), Wf - 1.f);
      int xi1 = (int)fminf(fmaxf(ix0 + 1.f, 0.f), Wf - 1.f);
      int yi0 = (int)fminf(fmaxf(iy0, 0.f), Hf - 1.f);
      int yi1 = (int)fminf(fmaxf(iy0 + 1.f, 0.f), Hf - 1.f);
      int lb = (l == 0) ? LB0 : (l == 1) ? LB1 : (l == 2) ? LB2 : LB3;
      int ib = lb + (b * 6 + cam) * Wi * Hi * 256;
      float cw[4];
      int co[4];
      cw[0] = (vx0 && vy0) ? wy0 * wx0 : 0.f;
      cw[1] = (vx1 && vy0) ? wy0 * wx1 : 0.f;
      cw[2] = (vx0 && vy1) ? wy1 * wx0 : 0.f;
      cw[3] = (vx1 && vy1) ? wy1 * wx1 : 0.f;
      co[0] = ib + (yi0 * Wi + xi0) * 256;
      co[1] = ib + (yi0 * Wi + xi1) * 256;
      co[2] = ib + (yi1 * Wi + xi0) * 256;
      co[3] = ib + (yi1 * Wi + xi1) * 256;
      unsigned short sw8 = (unsigned short)(s * 8);
#pragma unroll
      for (int k = 0; k < 4; ++k) {
        bool v = lv && (cw[k] != 0.f);
        unsigned long long mb = __ballot(v);
        int pos = cnt + __popcll(mb & ((1ull << lane) - 1ull));
        if (v) {
          centry[ebase + pos] = make_int2(co[k], __float_as_int(cw[k]));
          csS[ebase + pos] = sw8;
        }
        cnt += (int)__popcll(mb);
      }
    }
    if (cnt & 1) {
      if (lane == 0) {
        centry[ebase + cnt] = make_int2(0, 0);
        csS[ebase + cnt] = 0;
      }
      cnt++;
    }
  }
  // no barrier needed: each wave reads only its own segment below

  // --- phase 6: branch-free fp8 gather main loop ---
  int half = lane >> 5, l32 = lane & 31;
  int ch = l32 * 8;
  int g = l32 >> 2;
  float acc[8];
#pragma unroll
  for (int j = 0; j < 8; ++j) acc[j] = 0.f;
  {
    int ebase = w * 312;
    int nIter = cnt >> 1;
#pragma unroll 8
    for (int i = 0; i < nIter; ++i) {
      int idx = ebase + 2 * i + half;
      int2 e = centry[idx];
      float wgt_s = swgt[(int)csS[idx] + g];
      float cw = __int_as_float(e.y) * wgt_s;
      int2 u = *reinterpret_cast<const int2*>(fmws + e.x + ch);
      floatx2 p0 = __builtin_amdgcn_cvt_pk_f32_fp8(u.x, false);
      floatx2 p1 = __builtin_amdgcn_cvt_pk_f32_fp8(u.x, true);
      floatx2 p2 = __builtin_amdgcn_cvt_pk_f32_fp8(u.y, false);
      floatx2 p3 = __builtin_amdgcn_cvt_pk_f32_fp8(u.y, true);
      acc[0] = fmaf(cw, p0.x, acc[0]);
      acc[1] = fmaf(cw, p0.y, acc[1]);
      acc[2] = fmaf(cw, p1.x, acc[2]);
      acc[3] = fmaf(cw, p1.y, acc[3]);
      acc[4] = fmaf(cw, p2.x, acc[4]);
      acc[5] = fmaf(cw, p2.y, acc[5]);
      acc[6] = fmaf(cw, p3.x, acc[6]);
      acc[7] = fmaf(cw, p3.y, acc[7]);
    }
  }
  {
    int row = w * 2 + half;
    float4 v0 = make_float4(acc[0], acc[1], acc[2], acc[3]);
    float4 v1 = make_float4(acc[4], acc[5], acc[6], acc[7]);
    *reinterpret_cast<float4*>(&partS[row][ch]) = v0;
    *reinterpret_cast<float4*>(&partS[row][ch + 4]) = v1;
  }
  __syncthreads();

  // --- phase 7: cross-wave reduce + fused W_out epilogue ---
  float fv = 0.f;
#pragma unroll
  for (int r = 0; r < 8; ++r) fv += partS[r][t];
  fusedS[t] = fv;
  __syncthreads();

  float o = bout[t] + IF[(size_t)bn * 256 + t];
#pragma unroll 8
  for (int d = 0; d < 256; ++d)
    o = fmaf(fusedS[d], Wout[d * 256 + t], o);
  out[(size_t)bn * 256 + t] = o;
}

// ---------------------------------------------------------------------------
// Fallback path (small ws): logits GEMM + softmax + points + f32 NCHW agg
// ---------------------------------------------------------------------------
__global__ __launch_bounds__(256) void dfa_logits_gemm_fb(
    const float* __restrict__ IF, const float* __restrict__ AE,
    const float* __restrict__ Wwfc, const float* __restrict__ bwfc,
    float* __restrict__ logits) {
  __shared__ float feat_t[256][16];
  int t = threadIdx.x;
  int a0 = blockIdx.x * 15;
  int col = blockIdx.y * 256 + t;
  bool cv = col < C_NCOL;
#pragma unroll
  for (int a = 0; a < 15; ++a) {
    int bn = a0 + a;
    feat_t[t][a] = IF[(size_t)bn * 256 + t] + AE[(size_t)bn * 256 + t];
  }
  feat_t[t][15] = 0.f;
  __syncthreads();
  float acc[15];
  float bias = cv ? bwfc[col] : 0.f;
#pragma unroll
  for (int a = 0; a < 15; ++a) acc[a] = bias;
  const float* wp = Wwfc + col;
#pragma unroll 8
  for (int d = 0; d < 256; ++d) {
    float wv = cv ? wp[(size_t)d * C_NCOL] : 0.f;
#pragma unroll
    for (int a = 0; a < 15; ++a) acc[a] = fmaf(feat_t[d][a], wv, acc[a]);
  }
  if (cv) {
#pragma unroll
    for (int a = 0; a < 15; ++a)
      logits[(size_t)(a0 + a) * C_NCOL + col] = acc[a];
  }
}

__global__ __launch_bounds__(256) void dfa_softmax(float* __restrict__ wgt) {
  int bn = blockIdx.x;
  float* w = wgt + (size_t)bn * C_NCOL;
  __shared__ float buf[C_NCOL];
  int t = threadIdx.x;
  for (int i = t; i < C_NCOL; i += 256) buf[i] = w[i];
  __syncthreads();
  int g = t >> 5, lane = t & 31;
  float m = -1e30f;
  for (int s = lane; s < C_NSLOT; s += 32) m = fmaxf(m, buf[s * 8 + g]);
#pragma unroll
  for (int off = 16; off; off >>= 1) m = fmaxf(m, __shfl_xor(m, off, 32));
  float sum = 0.f;
  for (int s = lane; s < C_NSLOT; s += 32) {
    float e = expf(buf[s * 8 + g] - m);
    buf[s * 8 + g] = e;
    sum += e;
  }
#pragma unroll
  for (int off = 16; off; off >>= 1) sum += __shfl_xor(sum, off, 32);
  float inv = 1.f / sum;
  for (int s = lane; s < C_NSLOT; s += 32) w[s * 8 + g] = buf[s * 8 + g] * inv;
}

__global__ __launch_bounds__(128) void dfa_points(
    const float* __restrict__ IF, const float* __restrict__ anchor,
    const float* __restrict__ Wkps, const float* __restrict__ bkps,
    const float* __restrict__ projm, float2* __restrict__ grid) {
  int bn = blockIdx.x;
  int b = bn / C_NA;
  int t = threadIdx.x;
  __shared__ float kp[13][3];
  if (t < 39) {
    float acc = bkps[t];
    const float* f = IF + (size_t)bn * 256;
    for (int d = 0; d < 256; ++d) acc = fmaf(f[d], Wkps[d * 39 + t], acc);
    int p = t / 3, ax = t % 3;
    kp[p][ax] = anchor[(size_t)bn * 256 + ax] + acc;
  }
  __syncthreads();
  if (t < 78) {
    int c = t / 13, p = t % 13;
    const float* M = projm + (size_t)(b * 6 + c) * 16;
    float kx = kp[p][0], ky = kp[p][1], kz = kp[p][2];
    float x = M[0] * kx + M[1] * ky + M[2] * kz + M[3];
    float y = M[4] * kx + M[5] * ky + M[6] * kz + M[7];
    float z = M[8] * kx + M[9] * ky + M[10] * kz + M[11];
    float zc = fmaxf(z, 1e-5f);
    float inv = 1.0f / zc;
    grid[(size_t)bn * 78 + t] = make_float2(x * inv, y * inv);
  }
}

struct __align__(16) SlotInfo { int o[4]; float w[4]; };

__global__ __launch_bounds__(256) void dfa_agg_fb(
    const float* __restrict__ fm0, const float* __restrict__ fm1,
    const float* __restrict__ fm2, const float* __restrict__ fm3,
    const float2* __restrict__ grid, const float* __restrict__ wgt,
    const float* __restrict__ IF, const float* __restrict__ Wout,
    const float* __restrict__ bout, float* __restrict__ out) {
  int bn = blockIdx.x;
  int b = bn / C_NA;
  int t = threadIdx.x;
  int w = t >> 6, lane = t & 63;

  __shared__ SlotInfo slot[C_NSLOT];
  __shared__ int sflag[C_NSLOT];
  __shared__ float swgt[C_NCOL];
  __shared__ float part[4][256];
  __shared__ float fused[256];

  for (int i = t; i < C_NCOL; i += 256) swgt[i] = wgt[(size_t)bn * C_NCOL + i];

  for (int s = t; s < C_NSLOT; s += 256) {
    int c = s / 52, r = s % 52, l = r / 13, p = r % 13;
    float2 g2 = grid[(size_t)bn * 78 + c * 13 + p];
    int Wi = (l == 0) ? 176 : (l == 1) ? 88 : (l == 2) ? 44 : 22;
    int Hi = (l == 0) ? 64 : (l == 1) ? 32 : (l == 2) ? 16 : 8;
    float Wf = (float)Wi, Hf = (float)Hi;
    float ix = ((g2.x + 1.0f) * Wf - 1.0f) * 0.5f;
    float iy = ((g2.y + 1.0f) * Hf - 1.0f) * 0.5f;
    float ix0 = floorf(ix), iy0 = floorf(iy);
    float wx1 = ix - ix0, wy1 = iy - iy0;
    float wx0 = 1.f - wx1, wy0 = 1.f - wy1;
    bool vx0 = (ix0 >= 0.f) && (ix0 < Wf);
    bool vx1 = (ix0 + 1.f >= 0.f) && (ix0 + 1.f < Wf);
    bool vy0 = (iy0 >= 0.f) && (iy0 < Hf);
    bool vy1 = (iy0 + 1.f >= 0.f) && (iy0 + 1.f < Hf);
    int xi0 = (int)fminf(fmaxf(ix0, 0.f), Wf - 1.f);
    int xi1 = (int)fminf(fmaxf(ix0 + 1.f, 0.f), Wf - 1.f);
    int yi0 = (int)fminf(fmaxf(iy0, 0.f), Hf - 1.f);
    int yi1 = (int)fminf(fmaxf(iy0 + 1.f, 0.f), Hf - 1.f);
    int img = b * 6 + c;
    int HW = Wi * Hi;
    SlotInfo si;
    int ib = img * 256 * HW;
    si.o[0] = ib + yi0 * Wi + xi0;
    si.o[1] = ib + yi0 * Wi + xi1;
    si.o[2] = ib + yi1 * Wi + xi0;
    si.o[3] = ib + yi1 * Wi + xi1;
    si.w[0] = (vx0 && vy0) ? wy0 * wx0 : 0.f;
    si.w[1] = (vx1 && vy0) ? wy0 * wx1 : 0.f;
    si.w[2] = (vx0 && vy1) ? wy1 * wx0 : 0.f;
    si.w[3] = (vx1 && vy1) ? wy1 * wx1 : 0.f;
    slot[s] = si;
    sflag[s] = (si.w[0] + si.w[1] + si.w[2] + si.w[3] == 0.f) ? -1 : l;
  }
  __syncthreads();

  int g = lane >> 3;
  int ch = lane * 4;
  float4 acc = make_float4(0.f, 0.f, 0.f, 0.f);
  for (int s = w; s < C_NSLOT; s += 4) {
    int fl = sflag[s];
    if (fl < 0) continue;
    SlotInfo si = slot[s];
    float wg = swgt[s * 8 + g];
    const float* fp = (fl == 0) ? fm0 : (fl == 1) ? fm1 : (fl == 2) ? fm2 : fm3;
    int HW = (fl == 0) ? 11264 : (fl == 1) ? 2816 : (fl == 2) ? 704 : 176;
    float4 sv = make_float4(0.f, 0.f, 0.f, 0.f);
#pragma unroll
    for (int k = 0; k < 4; ++k) {
      if (si.w[k] != 0.f) {
        sv.x = fmaf(si.w[k], fp[si.o[k] + (size_t)(ch + 0) * HW], sv.x);
        sv.y = fmaf(si.w[k], fp[si.o[k] + (size_t)(ch + 1) * HW], sv.y);
        sv.z = fmaf(si.w[k], fp[si.o[k] + (size_t)(ch + 2) * HW], sv.z);
        sv.w = fmaf(si.w[k], fp[si.o[k] + (size_t)(ch + 3) * HW], sv.w);
      }
    }
    acc.x = fmaf(sv.x, wg, acc.x);
    acc.y = fmaf(sv.y, wg, acc.y);
    acc.z = fmaf(sv.z, wg, acc.z);
    acc.w = fmaf(sv.w, wg, acc.w);
  }
  *reinterpret_cast<float4*>(&part[w][ch]) = acc;
  __syncthreads();

  fused[t] = part[0][t] + part[1][t] + part[2][t] + part[3][t];
  __syncthreads();

  float o = bout[t] + IF[(size_t)bn * 256 + t];
#pragma unroll 4
  for (int d = 0; d < 256; ++d)
    o = fmaf(fused[d], Wout[d * 256 + t], o);
  out[(size_t)bn * 256 + t] = o;
}

// ---------------------------------------------------------------------------
extern "C" void kernel_launch(void* const* d_in, const int* in_sizes, int n_in,
                              void* d_out, int out_size, void* d_ws, size_t ws_size,
                              hipStream_t stream) {
  const float* IF     = (const float*)d_in[0];
  const float* anchor = (const float*)d_in[1];
  const float* AE     = (const float*)d_in[2];
  const float* fm0    = (const float*)d_in[3];
  const float* fm1    = (const float*)d_in[4];
  const float* fm2    = (const float*)d_in[5];
  const float* fm3    = (const float*)d_in[6];
  const float* projm  = (const float*)d_in[7];
  const float* Wkps   = (const float*)d_in[8];
  const float* bkps   = (const float*)d_in[9];
  const float* Wwfc   = (const float*)d_in[10];
  const float* bwfc   = (const float*)d_in[11];
  const float* Wout   = (const float*)d_in[12];
  const float* bout   = (const float*)d_in[13];
  float* out = (float*)d_out;
  char* ws = (char*)d_ws;

  bool full = ws_size >= (FM8_WS_BYTES + WGT_WS_BYTES);
  if (full) {
    unsigned char* fmws = (unsigned char*)ws;
    float* wgt = (float*)(ws + FM8_WS_BYTES);
    dfa_stage1<<<12432, 256, 0, stream>>>(fm0, fm1, fm2, fm3, fmws,
                                          IF, AE, Wwfc, bwfc, wgt);
    dfa_agg_full<<<1800, 256, 0, stream>>>(fmws, wgt, IF, anchor, Wkps, bkps,
                                           projm, Wout, bout, out);
  } else {
    float* wgt  = (float*)ws;
    float2* grd = (float2*)(ws + WGT_WS_BYTES);
    dfa_logits_gemm_fb<<<dim3(120, 10), 256, 0, stream>>>(IF, AE, Wwfc, bwfc, wgt);
    dfa_softmax<<<1800, 256, 0, stream>>>(wgt);
    dfa_points<<<1800, 128, 0, stream>>>(IF, anchor, Wkps, bkps, projm, grd);
    dfa_agg_fb<<<1800, 256, 0, stream>>>(fm0, fm1, fm2, fm3, grd, wgt,
                                         IF, Wout, bout, out);
  }
}